// Round 9
// baseline (663.824 us; speedup 1.0000x reference)
//
#include <hip/hip_runtime.h>
#include <hip/hip_bf16.h>
#include <stdint.h>

#define L_SEQ 8192
#define S_SEQ 512
#define DIM   2048
#define CTX   4096
#define NH    16
#define HD    128

typedef __bf16 bf16_t;
typedef bf16_t bf16x8 __attribute__((ext_vector_type(8)));
typedef float  f32x4_t __attribute__((ext_vector_type(4)));
typedef float  f32x16_t __attribute__((ext_vector_type(16)));

__device__ __forceinline__ ushort f2b(float f) {
  union { float f; uint32_t u; } v; v.f = f;
  uint32_t u = v.u;
  uint32_t r = (u + 0x7fffu + ((u >> 16) & 1u)) >> 16;
  return (ushort)r;
}
__device__ __forceinline__ uint32_t pk2(float a, float b) {
  return (uint32_t)f2b(a) | ((uint32_t)f2b(b) << 16);
}
__device__ __forceinline__ float b2f(ushort u) {
  union { uint32_t u; float f; } v; v.u = ((uint32_t)u) << 16;
  return v.f;
}
__device__ __forceinline__ void gll16(const ushort* g, ushort* l) {
  __builtin_amdgcn_global_load_lds((const __attribute__((address_space(1))) void*)g,
                                   (__attribute__((address_space(3))) void*)l, 16, 0, 0);
}

// ---------------- elementwise cast fp32 -> bf16 (ctx only now) ----------------
__global__ __launch_bounds__(256) void k_cast(const float* __restrict__ in,
                                              ushort* __restrict__ out) {
  const size_t i = ((size_t)blockIdx.x * 256 + threadIdx.x) * 8;
  float4 a = *(const float4*)(in + i);
  float4 b = *(const float4*)(in + i + 4);
  uint4 r;
  r.x = pk2(a.x, a.y); r.y = pk2(a.z, a.w);
  r.z = pk2(b.x, b.y); r.w = pk2(b.z, b.w);
  *(uint4*)(out + i) = r;
}

// ---------------- transpose + cast fp32 [K][N] -> bf16 [N][K] ----------------
__global__ __launch_bounds__(256) void k_tcast(const float* __restrict__ src,
                                               ushort* __restrict__ dst, int K, int N) {
  __shared__ float t[32][33];
  int tx = threadIdx.x, ty = threadIdx.y;
  int n0 = blockIdx.x * 32, k0 = blockIdx.y * 32;
#pragma unroll
  for (int i = 0; i < 4; i++)
    t[ty + 8 * i][tx] = src[(size_t)(k0 + ty + 8 * i) * N + n0 + tx];
  __syncthreads();
#pragma unroll
  for (int i = 0; i < 4; i++)
    dst[(size_t)(n0 + ty + 8 * i) * K + k0 + tx] = f2b(t[tx][ty + 8 * i]);
}

// ---------------- RMSNorm row kernel: bf16 [rows][2048] -> bf16, fused extra scale ----
__global__ __launch_bounds__(256) void k_rmsnorm(const ushort* __restrict__ in,
                                                 ushort* __restrict__ out,
                                                 const float* __restrict__ g, float scale) {
  const int row = blockIdx.x, tid = threadIdx.x;
  uint4 v = *(const uint4*)(in + (size_t)row * DIM + tid * 8);
  const uint32_t* vu = (const uint32_t*)&v;
  float f[8];
#pragma unroll
  for (int i = 0; i < 4; i++) {
    f[2 * i]     = b2f((ushort)(vu[i] & 0xffffu));
    f[2 * i + 1] = b2f((ushort)(vu[i] >> 16));
  }
  float s = 0.f;
#pragma unroll
  for (int i = 0; i < 8; i++) s += f[i] * f[i];
#pragma unroll
  for (int off = 32; off; off >>= 1) s += __shfl_down(s, off);
  __shared__ float wsum[4];
  __shared__ float rtot;
  if ((tid & 63) == 0) wsum[tid >> 6] = s;
  __syncthreads();
  if (tid == 0)
    rtot = rsqrtf((wsum[0] + wsum[1] + wsum[2] + wsum[3]) * (1.0f / DIM) + 1e-6f);
  __syncthreads();
  const float rms = rtot * scale;
  const float* gp = g + tid * 8;
  float4 g0 = *(const float4*)gp, g1 = *(const float4*)(gp + 4);
  ushort r[8];
  r[0] = f2b(f[0] * rms * g0.x); r[1] = f2b(f[1] * rms * g0.y);
  r[2] = f2b(f[2] * rms * g0.z); r[3] = f2b(f[3] * rms * g0.w);
  r[4] = f2b(f[4] * rms * g1.x); r[5] = f2b(f[5] * rms * g1.y);
  r[6] = f2b(f[6] * rms * g1.z); r[7] = f2b(f[7] * rms * g1.w);
  *(uint4*)(out + (size_t)row * DIM + tid * 8) = *(uint4*)r;
}

// ======================= 256x256 8-wave 4-phase GEMM =======================
// AF32=1: A is fp32; reg-staged (issue f4 loads at P0, cvt+ds_write at P3) —
// fuses the x cast into the GEMM. AF32=0: A bf16 via global_load_lds (burst P0).
// vmcnt bookkeeping (AF32): P0 issues 8 A-loads + 4 B-gll16 -> vmcnt(12) drains
// prior tile's 4 B; P3 vmcnt(4) drains this iter's 8 A-loads, then cvt+write.
template <int OUT_MODE, int AF32>
__global__ __launch_bounds__(512, 2) void k_gemm256(const ushort* __restrict__ A,
                                                    const ushort* __restrict__ Bt,
                                                    const float* __restrict__ bias,
                                                    void* __restrict__ outp,
                                                    int M, int N, int K) {
  __shared__ __align__(16) ushort lds[65536];  // 128 KB
  const int tid = threadIdx.x;
  const int l = tid & 63, wid = tid >> 6;
  const int wm = wid >> 2, wn = wid & 3;
  const int lr = l & 15, lq = l >> 4;

  const int nwg = gridDim.x * gridDim.y;
  const int bid = blockIdx.y * gridDim.x + blockIdx.x;
  const int swz = (bid & 7) * (nwg >> 3) + (bid >> 3);
  const int m0 = (swz / gridDim.x) * 256, n0 = (swz % gridDim.x) * 256;

  f32x4_t acc[8][4];
#pragma unroll
  for (int i = 0; i < 8; i++)
#pragma unroll
    for (int j = 0; j < 4; j++) acc[i][j] = f32x4_t{0.f, 0.f, 0.f, 0.f};

  const int srow = l >> 3;
  const int schunk = ((l & 7) ^ (srow & 7)) * 8;  // source pre-swizzle (rule 21)
  auto stage = [&](int buf, int tile, int mat, int h) {
    const ushort* gp = mat ? Bt : A;
    const int rn0 = mat ? n0 : m0;
    const size_t r0 = (size_t)(rn0 + h * 128 + wid * 8 + srow);
    const ushort* g0 = gp + r0 * K + tile * 64 + schunk;
    ushort* l0 = &lds[buf * 32768 + mat * 16384 + (h * 128 + wid * 8) * 64];
    gll16(g0, l0);
    gll16(g0 + (size_t)64 * K, l0 + 64 * 64);
  };
  // AF32: fp32 A loads (4 row-groups x 2 float4), same chunk map as gll16 dest
  float4 ar[8];
  auto loadA = [&](int tile) {
    const float* Af = (const float*)A;
#pragma unroll
    for (int i = 0; i < 4; i++) {
      const float* p = Af + (size_t)(m0 + i * 64 + wid * 8 + srow) * K + tile * 64 + schunk;
      ar[2 * i]     = *(const float4*)p;
      ar[2 * i + 1] = *(const float4*)(p + 4);
    }
  };
  auto writeA = [&](int buf) {
#pragma unroll
    for (int i = 0; i < 4; i++) {
      uint4 w;
      w.x = pk2(ar[2 * i].x, ar[2 * i].y);
      w.y = pk2(ar[2 * i].z, ar[2 * i].w);
      w.z = pk2(ar[2 * i + 1].x, ar[2 * i + 1].y);
      w.w = pk2(ar[2 * i + 1].z, ar[2 * i + 1].w);
      *(uint4*)(&lds[buf * 32768 + (i * 64 + wid * 8 + srow) * 64 + (l & 7) * 8]) = w;
    }
  };

  auto rdA = [&](int buf, int mf, int ks) -> bf16x8 {
    const int R = wm * 128 + mf * 16 + lr;
    return *(const bf16x8*)(&lds[buf * 32768 + R * 64 + (((ks * 4 + lq) ^ (R & 7)) * 8)]);
  };
  auto rdB = [&](int buf, int nf, int ks) -> bf16x8 {
    const int R = wn * 64 + nf * 16 + lr;
    return *(const bf16x8*)(&lds[buf * 32768 + 16384 + R * 64 + (((ks * 4 + lq) ^ (R & 7)) * 8)]);
  };

  const int NT = K >> 6;
  // prologue: tile 0 into buf 0
  if constexpr (AF32) {
    loadA(0);
    stage(0, 0, 1, 0); stage(0, 0, 1, 1);
    asm volatile("s_waitcnt vmcnt(4)" ::: "memory");  // A-loads done, B in flight
    writeA(0);
    asm volatile("s_waitcnt lgkmcnt(0)" ::: "memory");
    __builtin_amdgcn_sched_barrier(0);
  } else {
    stage(0, 0, 0, 0); stage(0, 0, 0, 1); stage(0, 0, 1, 0); stage(0, 0, 1, 1);
  }

  bf16x8 a[4][2], a2[4][2], b[2][2], b2[2][2];
  for (int kt = 0; kt < NT; kt++) {
    const int cur = kt & 1, nxt = cur ^ 1;
    const bool pf = (kt + 1 < NT);
    // ---- P0: issue next tile's loads -> counted vmcnt -> barrier -> Q0 ----
    if constexpr (AF32) {
      if (pf) {
        loadA(kt + 1);                                  // 8 f4 loads (oldest)
        stage(nxt, kt + 1, 1, 0); stage(nxt, kt + 1, 1, 1);  // 4 B gll16
        asm volatile("s_waitcnt vmcnt(12)" ::: "memory");    // drains tile cur's B
      } else {
        asm volatile("s_waitcnt vmcnt(0)" ::: "memory");
      }
    } else {
      if (pf) {
        stage(nxt, kt + 1, 0, 0); stage(nxt, kt + 1, 0, 1);
        stage(nxt, kt + 1, 1, 0); stage(nxt, kt + 1, 1, 1);
        asm volatile("s_waitcnt vmcnt(8)" ::: "memory");
      } else {
        asm volatile("s_waitcnt vmcnt(0)" ::: "memory");
      }
    }
    __builtin_amdgcn_sched_barrier(0);
    __builtin_amdgcn_s_barrier();
    __builtin_amdgcn_sched_barrier(0);
#pragma unroll
    for (int mf = 0; mf < 4; mf++) { a[mf][0] = rdA(cur, mf, 0); a[mf][1] = rdA(cur, mf, 1); }
#pragma unroll
    for (int nf = 0; nf < 2; nf++) { b[nf][0] = rdB(cur, nf, 0); b[nf][1] = rdB(cur, nf, 1); }
    __builtin_amdgcn_s_setprio(1);
#pragma unroll
    for (int mf = 0; mf < 4; mf++)
#pragma unroll
      for (int nf = 0; nf < 2; nf++) {
        acc[mf][nf] = __builtin_amdgcn_mfma_f32_16x16x32_bf16(a[mf][0], b[nf][0], acc[mf][nf], 0, 0, 0);
        acc[mf][nf] = __builtin_amdgcn_mfma_f32_16x16x32_bf16(a[mf][1], b[nf][1], acc[mf][nf], 0, 0, 0);
      }
    __builtin_amdgcn_s_setprio(0);
    __builtin_amdgcn_sched_barrier(0);
    __builtin_amdgcn_s_barrier();
    __builtin_amdgcn_sched_barrier(0);
    // ---- P1: read a2 (mf4-7) -> barrier -> MFMA a2 x b ----
#pragma unroll
    for (int mf = 0; mf < 4; mf++) { a2[mf][0] = rdA(cur, mf + 4, 0); a2[mf][1] = rdA(cur, mf + 4, 1); }
    __builtin_amdgcn_sched_barrier(0);
    __builtin_amdgcn_s_barrier();
    __builtin_amdgcn_sched_barrier(0);
    __builtin_amdgcn_s_setprio(1);
#pragma unroll
    for (int mf = 0; mf < 4; mf++)
#pragma unroll
      for (int nf = 0; nf < 2; nf++) {
        acc[mf + 4][nf] = __builtin_amdgcn_mfma_f32_16x16x32_bf16(a2[mf][0], b[nf][0], acc[mf + 4][nf], 0, 0, 0);
        acc[mf + 4][nf] = __builtin_amdgcn_mfma_f32_16x16x32_bf16(a2[mf][1], b[nf][1], acc[mf + 4][nf], 0, 0, 0);
      }
    __builtin_amdgcn_s_setprio(0);
    __builtin_amdgcn_sched_barrier(0);
    __builtin_amdgcn_s_barrier();
    __builtin_amdgcn_sched_barrier(0);
    // ---- P2: read b2 (nf2-3) -> barrier -> MFMA a2 x b2 ----
#pragma unroll
    for (int nf = 0; nf < 2; nf++) { b2[nf][0] = rdB(cur, nf + 2, 0); b2[nf][1] = rdB(cur, nf + 2, 1); }
    __builtin_amdgcn_sched_barrier(0);
    __builtin_amdgcn_s_barrier();
    __builtin_amdgcn_sched_barrier(0);
    __builtin_amdgcn_s_setprio(1);
#pragma unroll
    for (int mf = 0; mf < 4; mf++)
#pragma unroll
      for (int nf = 0; nf < 2; nf++) {
        acc[mf + 4][nf + 2] = __builtin_amdgcn_mfma_f32_16x16x32_bf16(a2[mf][0], b2[nf][0], acc[mf + 4][nf + 2], 0, 0, 0);
        acc[mf + 4][nf + 2] = __builtin_amdgcn_mfma_f32_16x16x32_bf16(a2[mf][1], b2[nf][1], acc[mf + 4][nf + 2], 0, 0, 0);
      }
    __builtin_amdgcn_s_setprio(0);
    __builtin_amdgcn_sched_barrier(0);
    __builtin_amdgcn_s_barrier();
    __builtin_amdgcn_sched_barrier(0);
    // ---- P3: (AF32: drain A-loads, cvt+ds_write next A) -> MFMA a x b2 ----
    if constexpr (AF32) {
      if (pf) {
        asm volatile("s_waitcnt vmcnt(4)" ::: "memory");  // this iter's 8 A-loads done
        __builtin_amdgcn_sched_barrier(0);
        writeA(nxt);
      }
    }
    __builtin_amdgcn_s_setprio(1);
#pragma unroll
    for (int mf = 0; mf < 4; mf++)
#pragma unroll
      for (int nf = 0; nf < 2; nf++) {
        acc[mf][nf + 2] = __builtin_amdgcn_mfma_f32_16x16x32_bf16(a[mf][0], b2[nf][0], acc[mf][nf + 2], 0, 0, 0);
        acc[mf][nf + 2] = __builtin_amdgcn_mfma_f32_16x16x32_bf16(a[mf][1], b2[nf][1], acc[mf][nf + 2], 0, 0, 0);
      }
    __builtin_amdgcn_s_setprio(0);
    if constexpr (AF32) {
      asm volatile("s_waitcnt lgkmcnt(0)" ::: "memory");  // A ds_writes visible pre-barrier
    }
    __builtin_amdgcn_sched_barrier(0);
    __builtin_amdgcn_s_barrier();    // reads of cur done before next iter's restage
    __builtin_amdgcn_sched_barrier(0);
  }

#pragma unroll
  for (int nf = 0; nf < 4; nf++) {
    const int col = n0 + wn * 64 + nf * 16 + lr;
    const float bv = bias[col];
#pragma unroll
    for (int mf = 0; mf < 8; mf++) {
#pragma unroll
      for (int r = 0; r < 4; r++) {
        const int row = m0 + wm * 128 + mf * 16 + lq * 4 + r;
        const float v = acc[mf][nf][r] + bv;
        if constexpr (OUT_MODE == 0)
          ((float*)outp)[(size_t)row * N + col] = v;
        else
          ((ushort*)outp)[(size_t)row * N + col] = f2b(v);
      }
    }
  }
}

// ============ KV projection GEMM: M=512, N=4096, K=4096, depth-4 pipeline ============
__global__ __launch_bounds__(256) void k_gemmkv(const ushort* __restrict__ A,
                                                const ushort* __restrict__ Bt,
                                                const float* __restrict__ biasK,
                                                const float* __restrict__ biasV,
                                                ushort* __restrict__ outK,
                                                ushort* __restrict__ outVt) {
  __shared__ __align__(16) ushort As[4][128 * 32];  // 32 KB
  __shared__ __align__(16) ushort Bs[4][64 * 32];   // 16 KB
  const int tid = threadIdx.x;
  const int l = tid & 63, wid = tid >> 6;
  const int wr = wid >> 1, wc = wid & 1;
  const int lr = l & 15, lq = l >> 4;
  const int K = CTX, M = S_SEQ;

  const int bid = blockIdx.x;                 // grid = 256
  const int swz = (bid & 7) * 32 + (bid >> 3);
  const int n0 = (swz >> 2) * 64, m0 = (swz & 3) * 128;

  f32x4_t acc[4][2];
#pragma unroll
  for (int i = 0; i < 4; i++)
#pragma unroll
    for (int j = 0; j < 2; j++) acc[i][j] = f32x4_t{0.f, 0.f, 0.f, 0.f};

  const int srow = l >> 2;
  const int schunk = ((l & 3) ^ ((srow >> 1) & 3)) * 8;
  const ushort* gA = A  + (size_t)(m0 + srow) * K + schunk;
  const ushort* gB = Bt + (size_t)(n0 + wid * 16 + srow) * K + schunk;

  auto stage = [&](int buf, int kt) {
    const int ko = kt * 32;
    gll16(gA + (size_t)(wid * 16) * K + ko,      &As[buf][(wid * 16) * 32]);
    gll16(gA + (size_t)(64 + wid * 16) * K + ko, &As[buf][(64 + wid * 16) * 32]);
    gll16(gB + ko,                               &Bs[buf][(wid * 16) * 32]);
  };
  auto rdA = [&](int buf, int mi) -> bf16x8 {
    const int R = wr * 64 + mi * 16 + lr;
    return *(const bf16x8*)(&As[buf][R * 32 + ((lq ^ ((R >> 1) & 3)) * 8)]);
  };
  auto rdB = [&](int buf, int ni) -> bf16x8 {
    const int R = wc * 32 + ni * 16 + lr;
    return *(const bf16x8*)(&Bs[buf][R * 32 + ((lq ^ ((R >> 1) & 3)) * 8)]);
  };

  const int NT = K >> 5;  // 128
  stage(0, 0); stage(1, 1); stage(2, 2);
  for (int t = 0; t < NT; t++) {
    const int cur = t & 3;
    if (t + 3 < NT) { stage((t + 3) & 3, t + 3); asm volatile("s_waitcnt vmcnt(9)" ::: "memory"); }
    else if (t + 2 < NT) { asm volatile("s_waitcnt vmcnt(6)" ::: "memory"); }
    else if (t + 1 < NT) { asm volatile("s_waitcnt vmcnt(3)" ::: "memory"); }
    else                 { asm volatile("s_waitcnt vmcnt(0)" ::: "memory"); }
    __builtin_amdgcn_sched_barrier(0);
    __builtin_amdgcn_s_barrier();
    __builtin_amdgcn_sched_barrier(0);

    bf16x8 af[4], bfr[2];
#pragma unroll
    for (int mi = 0; mi < 4; mi++) af[mi] = rdA(cur, mi);
#pragma unroll
    for (int ni = 0; ni < 2; ni++) bfr[ni] = rdB(cur, ni);
    __builtin_amdgcn_s_setprio(1);
#pragma unroll
    for (int mi = 0; mi < 4; mi++)
#pragma unroll
      for (int ni = 0; ni < 2; ni++)
        acc[mi][ni] = __builtin_amdgcn_mfma_f32_16x16x32_bf16(af[mi], bfr[ni], acc[mi][ni], 0, 0, 0);
    __builtin_amdgcn_s_setprio(0);
    __builtin_amdgcn_sched_barrier(0);
    __builtin_amdgcn_s_barrier();
    __builtin_amdgcn_sched_barrier(0);
  }

#pragma unroll
  for (int mi = 0; mi < 4; mi++) {
#pragma unroll
    for (int ni = 0; ni < 2; ni++) {
      const int col = n0 + wc * 32 + ni * 16 + lr;
      const float bv = (col < DIM) ? biasK[col] : biasV[col - DIM];
#pragma unroll
      for (int r = 0; r < 4; r++) {
        const int row = m0 + wr * 64 + mi * 16 + lq * 4 + r;
        const float v = acc[mi][ni][r] + bv;
        if (col < DIM) outK[(size_t)row * DIM + col] = f2b(v);
        else           outVt[(size_t)(col - DIM) * M + row] = f2b(v);  // V^T
      }
    }
  }
}

// ============ Flash attention, swapped-operand 32x32x16, double-buffered K/V ============
// Per kv-tile: vmcnt(0) (loads issued a full compute-phase earlier) -> s_barrier ->
// issue next tile's 8 gll16 into buf^1 -> compute cur. One barrier per tile.
__global__ __launch_bounds__(256) void k_attn(const ushort* __restrict__ Qb,
                                              const ushort* __restrict__ Kb,
                                              const ushort* __restrict__ Vt,
                                              ushort* __restrict__ Ob) {
  __shared__ __align__(16) ushort smem[32768];  // 64KB: 2 x (Ks [64][128] + Vs [128][64])

  const int tid = threadIdx.x;
  const int l = tid & 63, wid = tid >> 6;
  const int lo = l & 31, hi = l >> 5;

  const int bid = blockIdx.x;                  // grid = 1024
  const int swz = (bid & 7) * 128 + (bid >> 3);
  const int h = swz >> 6;
  const int q0 = (swz & 63) * 128 + wid * 32;

  bf16x8 qf[8];
  {
    const ushort* qp = Qb + (size_t)(q0 + lo) * DIM + h * HD + hi * 8;
#pragma unroll
    for (int ds = 0; ds < 8; ds++) qf[ds] = *(const bf16x8*)(qp + ds * 16);
  }

  f32x16_t o[4] = {};          // O^T: lane q = lo, d = nt*32 + crow(r,hi)
  float m_run = -1e30f, l_run = 0.f;

  auto stageKV = [&](int kvb, int buf) {
    ushort* Ksb = smem + buf * 16384;
    ushort* Vsb = Ksb + 8192;
#pragma unroll
    for (int i = 0; i < 4; i++) {
      const int c = i * 256 + tid, row = c >> 4, cs = c & 15;
      gll16(Kb + (size_t)(kvb * 64 + row) * DIM + h * HD + ((cs ^ (row & 7)) * 8),
            Ksb + c * 8);
    }
#pragma unroll
    for (int i = 0; i < 4; i++) {
      const int c = i * 256 + tid, row = c >> 3, cs = c & 7;
      gll16(Vt + (size_t)(h * HD + row) * S_SEQ + kvb * 64 + ((cs ^ (row & 7)) * 8),
            Vsb + c * 8);
    }
  };

  stageKV(0, 0);
  for (int kvb = 0; kvb < S_SEQ / 64; kvb++) {
    const int cur = kvb & 1;
    asm volatile("s_waitcnt vmcnt(0)" ::: "memory");  // tile cur resident (own loads)
    __builtin_amdgcn_sched_barrier(0);
    __builtin_amdgcn_s_barrier();                     // all waves' loads resident;
    __builtin_amdgcn_sched_barrier(0);                // all done reading buf cur^1
    if (kvb + 1 < S_SEQ / 64) stageKV(kvb + 1, cur ^ 1);

    const ushort* Ks = smem + cur * 16384;
    const ushort* Vs = Ks + 8192;

    f32x16_t sA = {}, sB = {};
#pragma unroll
    for (int ds = 0; ds < 8; ds++) {
      const int ch = ((hi + ds * 2) ^ (lo & 7)) * 8;
      bf16x8 kA = *(const bf16x8*)(Ks + lo * 128 + ch);
      bf16x8 kB = *(const bf16x8*)(Ks + (32 + lo) * 128 + ch);
      sA = __builtin_amdgcn_mfma_f32_32x32x16_bf16(kA, qf[ds], sA, 0, 0, 0);
      sB = __builtin_amdgcn_mfma_f32_32x32x16_bf16(kB, qf[ds], sB, 0, 0, 0);
    }

    float p[32];
#pragma unroll
    for (int i = 0; i < 16; i++) { p[i] = sA[i]; p[16 + i] = sB[i]; }
    float pm = p[0];
#pragma unroll
    for (int i = 1; i < 32; i++) pm = fmaxf(pm, p[i]);
    pm = fmaxf(pm, __shfl_xor(pm, 32));
    const float mn = fmaxf(m_run, pm);
    const float corr = __expf(m_run - mn);
    m_run = mn;
    float ps = 0.f;
#pragma unroll
    for (int i = 0; i < 32; i++) { p[i] = __expf(p[i] - mn); ps += p[i]; }
    ps += __shfl_xor(ps, 32);
    l_run = l_run * corr + ps;
#pragma unroll
    for (int nt = 0; nt < 4; nt++) o[nt] *= corr;

    uint32_t c[16];
#pragma unroll
    for (int j = 0; j < 16; j++) c[j] = pk2(p[2 * j], p[2 * j + 1]);
    bf16x8 pf[4];
#pragma unroll
    for (int s = 0; s < 4; s++) {
      const uint32_t ca = c[4 * s], cb = c[4 * s + 1], cc = c[4 * s + 2], cd = c[4 * s + 3];
      const uint32_t sa = __shfl_xor(ca, 32), sb = __shfl_xor(cb, 32);
      const uint32_t sc = __shfl_xor(cc, 32), sd = __shfl_xor(cd, 32);
      union { uint32_t u[4]; bf16x8 v; } f;
      f.u[0] = hi ? sc : ca; f.u[1] = hi ? sd : cb;
      f.u[2] = hi ? cc : sa; f.u[3] = hi ? cd : sb;
      pf[s] = f.v;
    }

#pragma unroll
    for (int nt = 0; nt < 4; nt++) {
      const int vrow = nt * 32 + lo;
#pragma unroll
      for (int s = 0; s < 4; s++) {
        bf16x8 vf = *(const bf16x8*)(Vs + vrow * 64 + (((s * 2 + hi) ^ (lo & 7)) * 8));
        o[nt] = __builtin_amdgcn_mfma_f32_32x32x16_bf16(vf, pf[s], o[nt], 0, 0, 0);
      }
    }
  }

  const float inv = 1.0f / l_run;
#pragma unroll
  for (int nt = 0; nt < 4; nt++) o[nt] *= inv;

  __syncthreads();  // all compute done; reuse smem as transpose buffers
  float* tb = (float*)smem + wid * (32 * 33);
  const int q2 = l >> 1, dh = (l & 1) * 16;
#pragma unroll
  for (int nt = 0; nt < 4; nt++) {
#pragma unroll
    for (int r = 0; r < 16; r++)
      tb[lo * 33 + ((r & 3) + 8 * (r >> 2) + 4 * hi)] = o[nt][r];
    asm volatile("s_waitcnt lgkmcnt(0)" ::: "memory");
    __builtin_amdgcn_sched_barrier(0);
    ushort tmp[16];
#pragma unroll
    for (int j = 0; j < 16; j++) tmp[j] = f2b(tb[q2 * 33 + dh + j]);
    asm volatile("s_waitcnt lgkmcnt(0)" ::: "memory");
    __builtin_amdgcn_sched_barrier(0);
    const size_t oaddr = (size_t)(q0 + q2) * DIM + h * HD + nt * 32 + dh;
    *(uint4*)(Ob + oaddr) = *(uint4*)tmp;
    *(uint4*)(Ob + oaddr + 8) = *(uint4*)(tmp + 8);
  }
}

extern "C" void kernel_launch(void* const* d_in, const int* in_sizes, int n_in,
                              void* d_out, int out_size, void* d_ws, size_t ws_size,
                              hipStream_t stream) {
  const float* x   = (const float*)d_in[0];
  const float* ctx = (const float*)d_in[1];
  const float* Wq  = (const float*)d_in[2];
  const float* bq  = (const float*)d_in[3];
  const float* Wk  = (const float*)d_in[4];
  const float* bk  = (const float*)d_in[5];
  const float* Wv  = (const float*)d_in[6];
  const float* bv  = (const float*)d_in[7];
  const float* Wo  = (const float*)d_in[8];
  const float* bo  = (const float*)d_in[9];
  const float* gq  = (const float*)d_in[10];
  const float* gk  = (const float*)d_in[11];

  char* ws = (char*)d_ws;
  ushort* wqt   = (ushort*)(ws);                 // [2048][2048] bf16   8.39MB
  ushort* wkt   = (ushort*)(ws + 8388608);       // [2048][4096] bf16  16.78MB  } adjacent =>
  ushort* wvt   = (ushort*)(ws + 25165824);      // [2048][4096] bf16  16.78MB  } [4096][4096] KV
  ushort* wot   = (ushort*)(ws + 41943040);      // [2048][2048] bf16   8.39MB
  ushort* qb    = (ushort*)(ws + 50331648);      // [8192][2048] bf16  33.55MB (normalized Q)
  ushort* kb    = (ushort*)(ws + 83886080);      // [512][2048]  bf16   2.10MB (normalized K)
  ushort* vt    = (ushort*)(ws + 85983232);      // [2048][512]  bf16   2.10MB (V^T per-head)
  ushort* ctxb  = (ushort*)(ws + 88080384);      // [512][4096]  bf16   4.19MB
  ushort* qraw  = (ushort*)(ws + 121634816);     // [8192][2048] bf16  33.55MB (pre-norm Q)
  ushort* kraw  = (ushort*)(ws + 121634816);     // [512][2048]  bf16   2.10MB (reuses qraw)
  ushort* attnb = (ushort*)(ws + 121634816);     // [8192][2048] bf16  33.55MB (reuses after K norm)

  // weight transposes + ctx cast
  k_tcast<<<dim3(DIM / 32, DIM / 32), dim3(32, 8), 0, stream>>>(Wq, wqt, DIM, DIM);
  k_tcast<<<dim3(DIM / 32, CTX / 32), dim3(32, 8), 0, stream>>>(Wk, wkt, CTX, DIM);
  k_tcast<<<dim3(DIM / 32, CTX / 32), dim3(32, 8), 0, stream>>>(Wv, wvt, CTX, DIM);
  k_tcast<<<dim3(DIM / 32, DIM / 32), dim3(32, 8), 0, stream>>>(Wo, wot, DIM, DIM);
  k_cast<<<S_SEQ * CTX / 8 / 256, 256, 0, stream>>>(ctx, ctxb);

  // Q path: q_raw = x@Wq + bq (bf16), x cast fused into A-staging (AF32=1)
  k_gemm256<1, 1><<<dim3(DIM / 256, L_SEQ / 256), 512, 0, stream>>>(
      (const ushort*)x, wqt, bq, qraw, L_SEQ, DIM, DIM);
  k_rmsnorm<<<L_SEQ, 256, 0, stream>>>(qraw, qb, gq, 0.08838834764831843f);
  // fused K+V projection: Bt = [Wk^T ; Wv^T] (adjacent in ws), N=4096
  k_gemmkv<<<256, 256, 0, stream>>>(ctxb, wkt, bk, bv, kraw, vt);
  k_rmsnorm<<<S_SEQ, 256, 0, stream>>>(kraw, kb, gk, 1.0f);
  // attention (swapped-operand 32x32 structure, double-buffered K/V)
  k_attn<<<L_SEQ / 128 * NH, 256, 0, stream>>>(qb, kb, vt, attnb);
  // out = attn @ Wo + bo (fp32)
  k_gemm256<0, 0><<<dim3(DIM / 256, L_SEQ / 256), 512, 0, stream>>>(
      attnb, wot, bo, d_out, L_SEQ, DIM, DIM);
}

// Round 10
// 325.796 us; speedup vs baseline: 2.0375x; 2.0375x over previous
//
#include <hip/hip_runtime.h>
#include <hip/hip_bf16.h>
#include <stdint.h>

#define L_SEQ 8192
#define S_SEQ 512
#define DIM   2048
#define CTX   4096
#define NH    16
#define HD    128

typedef __bf16 bf16_t;
typedef bf16_t bf16x8 __attribute__((ext_vector_type(8)));
typedef float  f32x4_t __attribute__((ext_vector_type(4)));
typedef float  f32x16_t __attribute__((ext_vector_type(16)));

__device__ __forceinline__ ushort f2b(float f) {
  union { float f; uint32_t u; } v; v.f = f;
  uint32_t u = v.u;
  uint32_t r = (u + 0x7fffu + ((u >> 16) & 1u)) >> 16;
  return (ushort)r;
}
__device__ __forceinline__ uint32_t pk2(float a, float b) {
  return (uint32_t)f2b(a) | ((uint32_t)f2b(b) << 16);
}
__device__ __forceinline__ float b2f(ushort u) {
  union { uint32_t u; float f; } v; v.u = ((uint32_t)u) << 16;
  return v.f;
}
__device__ __forceinline__ void gll16(const ushort* g, ushort* l) {
  __builtin_amdgcn_global_load_lds((const __attribute__((address_space(1))) void*)g,
                                   (__attribute__((address_space(3))) void*)l, 16, 0, 0);
}

// ============ fused preprocessing: x/ctx casts + 4 weight transposes ============
// block ranges: [0,8192) x-cast | [8192,9216) ctx-cast | [9216,13312) Wq |
// [13312,21504) Wk | [21504,29696) Wv | [29696,33792) Wo
__global__ __launch_bounds__(256) void k_prep(const float* __restrict__ x,
                                              const float* __restrict__ ctx,
                                              const float* __restrict__ Wq,
                                              const float* __restrict__ Wk,
                                              const float* __restrict__ Wv,
                                              const float* __restrict__ Wo,
                                              ushort* __restrict__ xb,
                                              ushort* __restrict__ ctxb,
                                              ushort* __restrict__ wqt,
                                              ushort* __restrict__ wkt,
                                              ushort* __restrict__ wvt,
                                              ushort* __restrict__ wot) {
  const int b = blockIdx.x;
  const int tid = threadIdx.x;
  if (b < 9216) {  // elementwise casts
    const float* src; ushort* dst; size_t i;
    if (b < 8192) { src = x;   dst = xb;   i = ((size_t)b * 256 + tid) * 8; }
    else          { src = ctx; dst = ctxb; i = ((size_t)(b - 8192) * 256 + tid) * 8; }
    float4 a = *(const float4*)(src + i);
    float4 c = *(const float4*)(src + i + 4);
    uint4 r;
    r.x = pk2(a.x, a.y); r.y = pk2(a.z, a.w);
    r.z = pk2(c.x, c.y); r.w = pk2(c.z, c.w);
    *(uint4*)(dst + i) = r;
    return;
  }
  // transpose + cast fp32 [K][2048] -> bf16 [2048][K]
  __shared__ float t[32][33];
  const float* src; ushort* dst; int K, ti;
  if (b < 13312)      { src = Wq; dst = wqt; K = DIM; ti = b - 9216; }
  else if (b < 21504) { src = Wk; dst = wkt; K = CTX; ti = b - 13312; }
  else if (b < 29696) { src = Wv; dst = wvt; K = CTX; ti = b - 21504; }
  else                { src = Wo; dst = wot; K = DIM; ti = b - 29696; }
  const int n0 = (ti & 63) * 32, k0 = (ti >> 6) * 32;
  const int tx = tid & 31, ty = tid >> 5;
#pragma unroll
  for (int i = 0; i < 4; i++)
    t[ty + 8 * i][tx] = src[(size_t)(k0 + ty + 8 * i) * DIM + n0 + tx];
  __syncthreads();
#pragma unroll
  for (int i = 0; i < 4; i++)
    dst[(size_t)(n0 + ty + 8 * i) * K + k0 + tx] = f2b(t[tx][ty + 8 * i]);
}

// ============ fused RMSNorm: rows [0,8192) = Q path, [8192,8704) = K path ============
__global__ __launch_bounds__(256) void k_rmsnorm2(const ushort* __restrict__ qraw,
                                                  const ushort* __restrict__ kraw,
                                                  ushort* __restrict__ qb,
                                                  ushort* __restrict__ kb,
                                                  const float* __restrict__ gq,
                                                  const float* __restrict__ gk) {
  int row = blockIdx.x;
  const int tid = threadIdx.x;
  const ushort* in; ushort* out; const float* g; float scale;
  if (row < L_SEQ) {
    in = qraw + (size_t)row * DIM; out = qb + (size_t)row * DIM;
    g = gq; scale = 0.08838834764831843f;  // softmax 1/sqrt(128) folded into Q
  } else {
    row -= L_SEQ;
    in = kraw + (size_t)row * DIM; out = kb + (size_t)row * DIM;
    g = gk; scale = 1.0f;
  }
  uint4 v = *(const uint4*)(in + tid * 8);
  const uint32_t* vu = (const uint32_t*)&v;
  float f[8];
#pragma unroll
  for (int i = 0; i < 4; i++) {
    f[2 * i]     = b2f((ushort)(vu[i] & 0xffffu));
    f[2 * i + 1] = b2f((ushort)(vu[i] >> 16));
  }
  float s = 0.f;
#pragma unroll
  for (int i = 0; i < 8; i++) s += f[i] * f[i];
#pragma unroll
  for (int off = 32; off; off >>= 1) s += __shfl_down(s, off);
  __shared__ float wsum[4];
  __shared__ float rtot;
  if ((tid & 63) == 0) wsum[tid >> 6] = s;
  __syncthreads();
  if (tid == 0)
    rtot = rsqrtf((wsum[0] + wsum[1] + wsum[2] + wsum[3]) * (1.0f / DIM) + 1e-6f);
  __syncthreads();
  const float rms = rtot * scale;
  const float* gp = g + tid * 8;
  float4 g0 = *(const float4*)gp, g1 = *(const float4*)(gp + 4);
  ushort r[8];
  r[0] = f2b(f[0] * rms * g0.x); r[1] = f2b(f[1] * rms * g0.y);
  r[2] = f2b(f[2] * rms * g0.z); r[3] = f2b(f[3] * rms * g0.w);
  r[4] = f2b(f[4] * rms * g1.x); r[5] = f2b(f[5] * rms * g1.y);
  r[6] = f2b(f[6] * rms * g1.z); r[7] = f2b(f[7] * rms * g1.w);
  *(uint4*)(out + tid * 8) = *(uint4*)r;
}

// ======================= 256x256 8-wave 4-phase GEMM (round-7 schedule) ==========
template <int OUT_MODE>
__global__ __launch_bounds__(512, 2) void k_gemm256(const ushort* __restrict__ A,
                                                    const ushort* __restrict__ Bt,
                                                    const float* __restrict__ bias,
                                                    void* __restrict__ outp,
                                                    int M, int N, int K) {
  __shared__ __align__(16) ushort lds[65536];  // 128 KB
  const int tid = threadIdx.x;
  const int l = tid & 63, wid = tid >> 6;
  const int wm = wid >> 2, wn = wid & 3;
  const int lr = l & 15, lq = l >> 4;

  const int nwg = gridDim.x * gridDim.y;
  const int bid = blockIdx.y * gridDim.x + blockIdx.x;
  const int swz = (bid & 7) * (nwg >> 3) + (bid >> 3);
  const int m0 = (swz / gridDim.x) * 256, n0 = (swz % gridDim.x) * 256;

  f32x4_t acc[8][4];
#pragma unroll
  for (int i = 0; i < 8; i++)
#pragma unroll
    for (int j = 0; j < 4; j++) acc[i][j] = f32x4_t{0.f, 0.f, 0.f, 0.f};

  const int srow = l >> 3;
  const int schunk = ((l & 7) ^ (srow & 7)) * 8;
  auto stage = [&](int buf, int tile, int mat, int h) {
    const ushort* gp = mat ? Bt : A;
    const int rn0 = mat ? n0 : m0;
    const size_t r0 = (size_t)(rn0 + h * 128 + wid * 8 + srow);
    const ushort* g0 = gp + r0 * K + tile * 64 + schunk;
    ushort* l0 = &lds[buf * 32768 + mat * 16384 + (h * 128 + wid * 8) * 64];
    gll16(g0, l0);
    gll16(g0 + (size_t)64 * K, l0 + 64 * 64);
  };

  auto rdA = [&](int buf, int mf, int ks) -> bf16x8 {
    const int R = wm * 128 + mf * 16 + lr;
    return *(const bf16x8*)(&lds[buf * 32768 + R * 64 + (((ks * 4 + lq) ^ (R & 7)) * 8)]);
  };
  auto rdB = [&](int buf, int nf, int ks) -> bf16x8 {
    const int R = wn * 64 + nf * 16 + lr;
    return *(const bf16x8*)(&lds[buf * 32768 + 16384 + R * 64 + (((ks * 4 + lq) ^ (R & 7)) * 8)]);
  };

  const int NT = K >> 6;
  stage(0, 0, 0, 0); stage(0, 0, 0, 1); stage(0, 0, 1, 0); stage(0, 0, 1, 1);

  bf16x8 a[4][2], a2[4][2], b[2][2], b2[2][2];
  for (int kt = 0; kt < NT; kt++) {
    const int cur = kt & 1, nxt = cur ^ 1;
    const bool pf = (kt + 1 < NT);
    if (pf) { stage(nxt, kt + 1, 0, 0); asm volatile("s_waitcnt vmcnt(2)" ::: "memory"); }
    else    { asm volatile("s_waitcnt vmcnt(0)" ::: "memory"); }
    __builtin_amdgcn_sched_barrier(0);
    __builtin_amdgcn_s_barrier();
    __builtin_amdgcn_sched_barrier(0);
#pragma unroll
    for (int mf = 0; mf < 4; mf++) { a[mf][0] = rdA(cur, mf, 0); a[mf][1] = rdA(cur, mf, 1); }
#pragma unroll
    for (int nf = 0; nf < 2; nf++) { b[nf][0] = rdB(cur, nf, 0); b[nf][1] = rdB(cur, nf, 1); }
    __builtin_amdgcn_s_setprio(1);
#pragma unroll
    for (int mf = 0; mf < 4; mf++)
#pragma unroll
      for (int nf = 0; nf < 2; nf++) {
        acc[mf][nf] = __builtin_amdgcn_mfma_f32_16x16x32_bf16(a[mf][0], b[nf][0], acc[mf][nf], 0, 0, 0);
        acc[mf][nf] = __builtin_amdgcn_mfma_f32_16x16x32_bf16(a[mf][1], b[nf][1], acc[mf][nf], 0, 0, 0);
      }
    __builtin_amdgcn_s_setprio(0);
    __builtin_amdgcn_sched_barrier(0);
    __builtin_amdgcn_s_barrier();
    __builtin_amdgcn_sched_barrier(0);
#pragma unroll
    for (int mf = 0; mf < 4; mf++) { a2[mf][0] = rdA(cur, mf + 4, 0); a2[mf][1] = rdA(cur, mf + 4, 1); }
    if (pf) stage(nxt, kt + 1, 0, 1);
    __builtin_amdgcn_sched_barrier(0);
    __builtin_amdgcn_s_barrier();
    __builtin_amdgcn_sched_barrier(0);
    __builtin_amdgcn_s_setprio(1);
#pragma unroll
    for (int mf = 0; mf < 4; mf++)
#pragma unroll
      for (int nf = 0; nf < 2; nf++) {
        acc[mf + 4][nf] = __builtin_amdgcn_mfma_f32_16x16x32_bf16(a2[mf][0], b[nf][0], acc[mf + 4][nf], 0, 0, 0);
        acc[mf + 4][nf] = __builtin_amdgcn_mfma_f32_16x16x32_bf16(a2[mf][1], b[nf][1], acc[mf + 4][nf], 0, 0, 0);
      }
    __builtin_amdgcn_s_setprio(0);
    __builtin_amdgcn_sched_barrier(0);
    __builtin_amdgcn_s_barrier();
    __builtin_amdgcn_sched_barrier(0);
#pragma unroll
    for (int nf = 0; nf < 2; nf++) { b2[nf][0] = rdB(cur, nf + 2, 0); b2[nf][1] = rdB(cur, nf + 2, 1); }
    if (pf) stage(nxt, kt + 1, 1, 0);
    __builtin_amdgcn_sched_barrier(0);
    __builtin_amdgcn_s_barrier();
    __builtin_amdgcn_sched_barrier(0);
    __builtin_amdgcn_s_setprio(1);
#pragma unroll
    for (int mf = 0; mf < 4; mf++)
#pragma unroll
      for (int nf = 0; nf < 2; nf++) {
        acc[mf + 4][nf + 2] = __builtin_amdgcn_mfma_f32_16x16x32_bf16(a2[mf][0], b2[nf][0], acc[mf + 4][nf + 2], 0, 0, 0);
        acc[mf + 4][nf + 2] = __builtin_amdgcn_mfma_f32_16x16x32_bf16(a2[mf][1], b2[nf][1], acc[mf + 4][nf + 2], 0, 0, 0);
      }
    __builtin_amdgcn_s_setprio(0);
    __builtin_amdgcn_sched_barrier(0);
    __builtin_amdgcn_s_barrier();
    __builtin_amdgcn_sched_barrier(0);
#pragma unroll
    for (int mf = 0; mf < 4; mf++) { a[mf][0] = rdA(cur, mf, 0); a[mf][1] = rdA(cur, mf, 1); }
    if (pf) stage(nxt, kt + 1, 1, 1);
    __builtin_amdgcn_sched_barrier(0);
    __builtin_amdgcn_s_barrier();
    __builtin_amdgcn_sched_barrier(0);
    __builtin_amdgcn_s_setprio(1);
#pragma unroll
    for (int mf = 0; mf < 4; mf++)
#pragma unroll
      for (int nf = 0; nf < 2; nf++) {
        acc[mf][nf + 2] = __builtin_amdgcn_mfma_f32_16x16x32_bf16(a[mf][0], b2[nf][0], acc[mf][nf + 2], 0, 0, 0);
        acc[mf][nf + 2] = __builtin_amdgcn_mfma_f32_16x16x32_bf16(a[mf][1], b2[nf][1], acc[mf][nf + 2], 0, 0, 0);
      }
    __builtin_amdgcn_s_setprio(0);
    __builtin_amdgcn_sched_barrier(0);
    __builtin_amdgcn_s_barrier();
    __builtin_amdgcn_sched_barrier(0);
  }

#pragma unroll
  for (int nf = 0; nf < 4; nf++) {
    const int col = n0 + wn * 64 + nf * 16 + lr;
    const float bv = bias[col];
#pragma unroll
    for (int mf = 0; mf < 8; mf++) {
#pragma unroll
      for (int r = 0; r < 4; r++) {
        const int row = m0 + wm * 128 + mf * 16 + lq * 4 + r;
        const float v = acc[mf][nf][r] + bv;
        if constexpr (OUT_MODE == 0)
          ((float*)outp)[(size_t)row * N + col] = v;
        else
          ((ushort*)outp)[(size_t)row * N + col] = f2b(v);
      }
    }
  }
}

// ============ KV projection GEMM: M=512, N=4096, K=4096, depth-4 pipeline ============
__global__ __launch_bounds__(256) void k_gemmkv(const ushort* __restrict__ A,
                                                const ushort* __restrict__ Bt,
                                                const float* __restrict__ biasK,
                                                const float* __restrict__ biasV,
                                                ushort* __restrict__ outK,
                                                ushort* __restrict__ outVt) {
  __shared__ __align__(16) ushort As[4][128 * 32];  // 32 KB
  __shared__ __align__(16) ushort Bs[4][64 * 32];   // 16 KB
  const int tid = threadIdx.x;
  const int l = tid & 63, wid = tid >> 6;
  const int wr = wid >> 1, wc = wid & 1;
  const int lr = l & 15, lq = l >> 4;
  const int K = CTX, M = S_SEQ;

  const int bid = blockIdx.x;                 // grid = 256
  const int swz = (bid & 7) * 32 + (bid >> 3);
  const int n0 = (swz >> 2) * 64, m0 = (swz & 3) * 128;

  f32x4_t acc[4][2];
#pragma unroll
  for (int i = 0; i < 4; i++)
#pragma unroll
    for (int j = 0; j < 2; j++) acc[i][j] = f32x4_t{0.f, 0.f, 0.f, 0.f};

  const int srow = l >> 2;
  const int schunk = ((l & 3) ^ ((srow >> 1) & 3)) * 8;
  const ushort* gA = A  + (size_t)(m0 + srow) * K + schunk;
  const ushort* gB = Bt + (size_t)(n0 + wid * 16 + srow) * K + schunk;

  auto stage = [&](int buf, int kt) {
    const int ko = kt * 32;
    gll16(gA + (size_t)(wid * 16) * K + ko,      &As[buf][(wid * 16) * 32]);
    gll16(gA + (size_t)(64 + wid * 16) * K + ko, &As[buf][(64 + wid * 16) * 32]);
    gll16(gB + ko,                               &Bs[buf][(wid * 16) * 32]);
  };
  auto rdA = [&](int buf, int mi) -> bf16x8 {
    const int R = wr * 64 + mi * 16 + lr;
    return *(const bf16x8*)(&As[buf][R * 32 + ((lq ^ ((R >> 1) & 3)) * 8)]);
  };
  auto rdB = [&](int buf, int ni) -> bf16x8 {
    const int R = wc * 32 + ni * 16 + lr;
    return *(const bf16x8*)(&Bs[buf][R * 32 + ((lq ^ ((R >> 1) & 3)) * 8)]);
  };

  const int NT = K >> 5;  // 128
  stage(0, 0); stage(1, 1); stage(2, 2);
  for (int t = 0; t < NT; t++) {
    const int cur = t & 3;
    if (t + 3 < NT) { stage((t + 3) & 3, t + 3); asm volatile("s_waitcnt vmcnt(9)" ::: "memory"); }
    else if (t + 2 < NT) { asm volatile("s_waitcnt vmcnt(6)" ::: "memory"); }
    else if (t + 1 < NT) { asm volatile("s_waitcnt vmcnt(3)" ::: "memory"); }
    else                 { asm volatile("s_waitcnt vmcnt(0)" ::: "memory"); }
    __builtin_amdgcn_sched_barrier(0);
    __builtin_amdgcn_s_barrier();
    __builtin_amdgcn_sched_barrier(0);

    bf16x8 af[4], bfr[2];
#pragma unroll
    for (int mi = 0; mi < 4; mi++) af[mi] = rdA(cur, mi);
#pragma unroll
    for (int ni = 0; ni < 2; ni++) bfr[ni] = rdB(cur, ni);
    __builtin_amdgcn_s_setprio(1);
#pragma unroll
    for (int mi = 0; mi < 4; mi++)
#pragma unroll
      for (int ni = 0; ni < 2; ni++)
        acc[mi][ni] = __builtin_amdgcn_mfma_f32_16x16x32_bf16(af[mi], bfr[ni], acc[mi][ni], 0, 0, 0);
    __builtin_amdgcn_s_setprio(0);
    __builtin_amdgcn_sched_barrier(0);
    __builtin_amdgcn_s_barrier();
    __builtin_amdgcn_sched_barrier(0);
  }

#pragma unroll
  for (int mi = 0; mi < 4; mi++) {
#pragma unroll
    for (int ni = 0; ni < 2; ni++) {
      const int col = n0 + wc * 32 + ni * 16 + lr;
      const float bv = (col < DIM) ? biasK[col] : biasV[col - DIM];
#pragma unroll
      for (int r = 0; r < 4; r++) {
        const int row = m0 + wr * 64 + mi * 16 + lq * 4 + r;
        const float v = acc[mi][ni][r] + bv;
        if (col < DIM) outK[(size_t)row * DIM + col] = f2b(v);
        else           outVt[(size_t)(col - DIM) * M + row] = f2b(v);  // V^T
      }
    }
  }
}

// ============ Flash attention, swapped-operand 32x32x16 (round-7 version) ============
__global__ __launch_bounds__(256) void k_attn(const ushort* __restrict__ Qb,
                                              const ushort* __restrict__ Kb,
                                              const ushort* __restrict__ Vt,
                                              ushort* __restrict__ Ob) {
  __shared__ __align__(16) ushort smem[16384];  // 32KB: Ks [64][128] + Vs [128][64]
  ushort* Ks = smem;
  ushort* Vs = smem + 64 * 128;

  const int tid = threadIdx.x;
  const int l = tid & 63, wid = tid >> 6;
  const int lo = l & 31, hi = l >> 5;

  const int bid = blockIdx.x;                  // grid = 1024
  const int swz = (bid & 7) * 128 + (bid >> 3);
  const int h = swz >> 6;
  const int q0 = (swz & 63) * 128 + wid * 32;

  bf16x8 qf[8];
  {
    const ushort* qp = Qb + (size_t)(q0 + lo) * DIM + h * HD + hi * 8;
#pragma unroll
    for (int ds = 0; ds < 8; ds++) qf[ds] = *(const bf16x8*)(qp + ds * 16);
  }

  f32x16_t o[4] = {};          // O^T: lane q = lo, d = nt*32 + crow(r,hi)
  float m_run = -1e30f, l_run = 0.f;

  for (int kvb = 0; kvb < S_SEQ / 64; kvb++) {
    __syncthreads();
#pragma unroll
    for (int i = 0; i < 4; i++) {
      const int c = i * 256 + tid, row = c >> 4, cs = c & 15;
      gll16(Kb + (size_t)(kvb * 64 + row) * DIM + h * HD + ((cs ^ (row & 7)) * 8),
            Ks + c * 8);
    }
#pragma unroll
    for (int i = 0; i < 4; i++) {
      const int c = i * 256 + tid, row = c >> 3, cs = c & 7;
      gll16(Vt + (size_t)(h * HD + row) * S_SEQ + kvb * 64 + ((cs ^ (row & 7)) * 8),
            Vs + c * 8);
    }
    __syncthreads();

    f32x16_t sA = {}, sB = {};
#pragma unroll
    for (int ds = 0; ds < 8; ds++) {
      const int ch = ((hi + ds * 2) ^ (lo & 7)) * 8;
      bf16x8 kA = *(const bf16x8*)(Ks + lo * 128 + ch);
      bf16x8 kB = *(const bf16x8*)(Ks + (32 + lo) * 128 + ch);
      sA = __builtin_amdgcn_mfma_f32_32x32x16_bf16(kA, qf[ds], sA, 0, 0, 0);
      sB = __builtin_amdgcn_mfma_f32_32x32x16_bf16(kB, qf[ds], sB, 0, 0, 0);
    }

    float p[32];
#pragma unroll
    for (int i = 0; i < 16; i++) { p[i] = sA[i]; p[16 + i] = sB[i]; }
    float pm = p[0];
#pragma unroll
    for (int i = 1; i < 32; i++) pm = fmaxf(pm, p[i]);
    pm = fmaxf(pm, __shfl_xor(pm, 32));
    const float mn = fmaxf(m_run, pm);
    const float corr = __expf(m_run - mn);
    m_run = mn;
    float ps = 0.f;
#pragma unroll
    for (int i = 0; i < 32; i++) { p[i] = __expf(p[i] - mn); ps += p[i]; }
    ps += __shfl_xor(ps, 32);
    l_run = l_run * corr + ps;
#pragma unroll
    for (int nt = 0; nt < 4; nt++) o[nt] *= corr;

    uint32_t c[16];
#pragma unroll
    for (int j = 0; j < 16; j++) c[j] = pk2(p[2 * j], p[2 * j + 1]);
    bf16x8 pf[4];
#pragma unroll
    for (int s = 0; s < 4; s++) {
      const uint32_t ca = c[4 * s], cb = c[4 * s + 1], cc = c[4 * s + 2], cd = c[4 * s + 3];
      const uint32_t sa = __shfl_xor(ca, 32), sb = __shfl_xor(cb, 32);
      const uint32_t sc = __shfl_xor(cc, 32), sd = __shfl_xor(cd, 32);
      union { uint32_t u[4]; bf16x8 v; } f;
      f.u[0] = hi ? sc : ca; f.u[1] = hi ? sd : cb;
      f.u[2] = hi ? cc : sa; f.u[3] = hi ? cd : sb;
      pf[s] = f.v;
    }

#pragma unroll
    for (int nt = 0; nt < 4; nt++) {
      const int vrow = nt * 32 + lo;
#pragma unroll
      for (int s = 0; s < 4; s++) {
        bf16x8 vf = *(const bf16x8*)(Vs + vrow * 64 + (((s * 2 + hi) ^ (lo & 7)) * 8));
        o[nt] = __builtin_amdgcn_mfma_f32_32x32x16_bf16(vf, pf[s], o[nt], 0, 0, 0);
      }
    }
  }

  const float inv = 1.0f / l_run;
#pragma unroll
  for (int nt = 0; nt < 4; nt++) o[nt] *= inv;

  __syncthreads();
  float* tb = (float*)smem + wid * (32 * 33);
  const int q2 = l >> 1, dh = (l & 1) * 16;
#pragma unroll
  for (int nt = 0; nt < 4; nt++) {
#pragma unroll
    for (int r = 0; r < 16; r++)
      tb[lo * 33 + ((r & 3) + 8 * (r >> 2) + 4 * hi)] = o[nt][r];
    asm volatile("s_waitcnt lgkmcnt(0)" ::: "memory");
    __builtin_amdgcn_sched_barrier(0);
    ushort tmp[16];
#pragma unroll
    for (int j = 0; j < 16; j++) tmp[j] = f2b(tb[q2 * 33 + dh + j]);
    asm volatile("s_waitcnt lgkmcnt(0)" ::: "memory");
    __builtin_amdgcn_sched_barrier(0);
    const size_t oaddr = (size_t)(q0 + q2) * DIM + h * HD + nt * 32 + dh;
    *(uint4*)(Ob + oaddr) = *(uint4*)tmp;
    *(uint4*)(Ob + oaddr + 8) = *(uint4*)(tmp + 8);
  }
}

extern "C" void kernel_launch(void* const* d_in, const int* in_sizes, int n_in,
                              void* d_out, int out_size, void* d_ws, size_t ws_size,
                              hipStream_t stream) {
  const float* x   = (const float*)d_in[0];
  const float* ctx = (const float*)d_in[1];
  const float* Wq  = (const float*)d_in[2];
  const float* bq  = (const float*)d_in[3];
  const float* Wk  = (const float*)d_in[4];
  const float* bk  = (const float*)d_in[5];
  const float* Wv  = (const float*)d_in[6];
  const float* bv  = (const float*)d_in[7];
  const float* Wo  = (const float*)d_in[8];
  const float* bo  = (const float*)d_in[9];
  const float* gq  = (const float*)d_in[10];
  const float* gk  = (const float*)d_in[11];

  char* ws = (char*)d_ws;
  ushort* wqt   = (ushort*)(ws);                 // [2048][2048] bf16   8.39MB
  ushort* wkt   = (ushort*)(ws + 8388608);       // [2048][4096] bf16  16.78MB } adjacent =>
  ushort* wvt   = (ushort*)(ws + 25165824);      // [2048][4096] bf16  16.78MB } [4096][4096] KV
  ushort* wot   = (ushort*)(ws + 41943040);      // [2048][2048] bf16   8.39MB
  ushort* qb    = (ushort*)(ws + 50331648);      // [8192][2048] bf16  33.55MB (normalized Q)
  ushort* ctxb  = (ushort*)(ws + 50331648);      // [512][4096]  bf16   4.19MB (aliases qb; dead before qb written)
  ushort* kb    = (ushort*)(ws + 83886080);      // [512][2048]  bf16   2.10MB (normalized K)
  ushort* vt    = (ushort*)(ws + 85983232);      // [2048][512]  bf16   2.10MB (V^T per-head)
  ushort* xb    = (ushort*)(ws + 88080384);      // [8192][2048] bf16  33.55MB (x cast)
  ushort* kraw  = (ushort*)(ws + 88080384);      // [512][2048]  bf16   2.10MB (aliases xb; xb dead after Qproj)
  ushort* attnb = (ushort*)(ws + 88080384);      // [8192][2048] bf16  33.55MB (aliases; kraw dead after rmsnorm)
  ushort* qraw  = (ushort*)(ws + 121634816);     // [8192][2048] bf16  33.55MB (pre-norm Q)

  // 1. all preprocessing fused: x/ctx casts + 4 weight transposes
  k_prep<<<33792, 256, 0, stream>>>(x, ctx, Wq, Wk, Wv, Wo,
                                    xb, ctxb, wqt, wkt, wvt, wot);
  // 2. Q projection: qraw = x@Wq + bq (bf16)
  k_gemm256<1><<<dim3(DIM / 256, L_SEQ / 256), 512, 0, stream>>>(xb, wqt, bq, qraw, L_SEQ, DIM, DIM);
  // 3. fused K+V projection: Bt = [Wk^T ; Wv^T], N=4096 (kraw overwrites dead xb)
  k_gemmkv<<<256, 256, 0, stream>>>(ctxb, wkt, bk, bv, kraw, vt);
  // 4. fused RMSNorm for Q (softmax scale folded) and K
  k_rmsnorm2<<<L_SEQ + S_SEQ, 256, 0, stream>>>(qraw, kraw, qb, kb, gq, gk);
  // 5. attention (swapped-operand 32x32 structure)
  k_attn<<<L_SEQ / 128 * NH, 256, 0, stream>>>(qb, kb, vt, attnb);
  // 6. out = attn @ Wo + bo (fp32)
  k_gemm256<0><<<dim3(DIM / 256, L_SEQ / 256), 512, 0, stream>>>(attnb, wot, bo, d_out, L_SEQ, DIM, DIM);
}

// Round 11
// 318.918 us; speedup vs baseline: 2.0815x; 1.0216x over previous
//
#include <hip/hip_runtime.h>
#include <hip/hip_bf16.h>
#include <stdint.h>

#define L_SEQ 8192
#define S_SEQ 512
#define DIM   2048
#define CTX   4096
#define NH    16
#define HD    128

typedef __bf16 bf16_t;
typedef bf16_t bf16x8 __attribute__((ext_vector_type(8)));
typedef float  f32x4_t __attribute__((ext_vector_type(4)));
typedef float  f32x16_t __attribute__((ext_vector_type(16)));

__device__ __forceinline__ ushort f2b(float f) {
  union { float f; uint32_t u; } v; v.f = f;
  uint32_t u = v.u;
  uint32_t r = (u + 0x7fffu + ((u >> 16) & 1u)) >> 16;
  return (ushort)r;
}
__device__ __forceinline__ uint32_t pk2(float a, float b) {
  return (uint32_t)f2b(a) | ((uint32_t)f2b(b) << 16);
}
__device__ __forceinline__ float b2f(ushort u) {
  union { uint32_t u; float f; } v; v.u = ((uint32_t)u) << 16;
  return v.f;
}
__device__ __forceinline__ void gll16(const ushort* g, ushort* l) {
  __builtin_amdgcn_global_load_lds((const __attribute__((address_space(1))) void*)g,
                                   (__attribute__((address_space(3))) void*)l, 16, 0, 0);
}

// ============ fused preprocessing: x/ctx casts + 4 weight transposes + G ============
// block ranges: [0,8192) x-cast | [8192,9216) ctx-cast | [9216,13312) Wq |
// [13312,21504) Wk | [21504,29696) Wv | [29696,33792) Wo | 33792: G = gq*gk/sqrt(128)
__global__ __launch_bounds__(256) void k_prep(const float* __restrict__ x,
                                              const float* __restrict__ ctx,
                                              const float* __restrict__ Wq,
                                              const float* __restrict__ Wk,
                                              const float* __restrict__ Wv,
                                              const float* __restrict__ Wo,
                                              const float* __restrict__ gq,
                                              const float* __restrict__ gk,
                                              ushort* __restrict__ xb,
                                              ushort* __restrict__ ctxb,
                                              ushort* __restrict__ wqt,
                                              ushort* __restrict__ wkt,
                                              ushort* __restrict__ wvt,
                                              ushort* __restrict__ wot,
                                              float* __restrict__ g2) {
  const int b = blockIdx.x;
  const int tid = threadIdx.x;
  if (b == 33792) {  // G vector
    const int d = tid * 8;
#pragma unroll
    for (int j = 0; j < 8; j++) g2[d + j] = gq[d + j] * gk[d + j] * 0.08838834764831843f;
    return;
  }
  if (b < 9216) {  // elementwise casts
    const float* src; ushort* dst; size_t i;
    if (b < 8192) { src = x;   dst = xb;   i = ((size_t)b * 256 + tid) * 8; }
    else          { src = ctx; dst = ctxb; i = ((size_t)(b - 8192) * 256 + tid) * 8; }
    float4 a = *(const float4*)(src + i);
    float4 c = *(const float4*)(src + i + 4);
    uint4 r;
    r.x = pk2(a.x, a.y); r.y = pk2(a.z, a.w);
    r.z = pk2(c.x, c.y); r.w = pk2(c.z, c.w);
    *(uint4*)(dst + i) = r;
    return;
  }
  // transpose + cast fp32 [K][2048] -> bf16 [2048][K]
  __shared__ float t[32][33];
  const float* src; ushort* dst; int K, ti;
  if (b < 13312)      { src = Wq; dst = wqt; K = DIM; ti = b - 9216; }
  else if (b < 21504) { src = Wk; dst = wkt; K = CTX; ti = b - 13312; }
  else if (b < 29696) { src = Wv; dst = wvt; K = CTX; ti = b - 21504; }
  else                { src = Wo; dst = wot; K = DIM; ti = b - 29696; }
  const int n0 = (ti & 63) * 32, k0 = (ti >> 6) * 32;
  const int tx = tid & 31, ty = tid >> 5;
#pragma unroll
  for (int i = 0; i < 4; i++)
    t[ty + 8 * i][tx] = src[(size_t)(k0 + ty + 8 * i) * DIM + n0 + tx];
  __syncthreads();
#pragma unroll
  for (int i = 0; i < 4; i++)
    dst[(size_t)(n0 + ty + 8 * i) * K + k0 + tx] = f2b(t[tx][ty + 8 * i]);
}

// ============ Q/K norm-factor kernel ============
// rows [0,8192): Q — compute per-row rsqrt(mean(q^2)+eps) into qscale (g_q folded
// into G, applied in attention). rows [8192,8704): K — write kb = kraw * rms
// (g_k folded into G on the Q side).
__global__ __launch_bounds__(256) void k_qknorm(const ushort* __restrict__ qraw,
                                                const ushort* __restrict__ kraw,
                                                float* __restrict__ qscale,
                                                ushort* __restrict__ kb) {
  const int row = blockIdx.x, tid = threadIdx.x;
  const bool isQ = (row < L_SEQ);
  const ushort* in = isQ ? qraw + (size_t)row * DIM
                         : kraw + (size_t)(row - L_SEQ) * DIM;
  uint4 v = *(const uint4*)(in + tid * 8);
  const uint32_t* vu = (const uint32_t*)&v;
  float f[8];
#pragma unroll
  for (int i = 0; i < 4; i++) {
    f[2 * i]     = b2f((ushort)(vu[i] & 0xffffu));
    f[2 * i + 1] = b2f((ushort)(vu[i] >> 16));
  }
  float s = 0.f;
#pragma unroll
  for (int i = 0; i < 8; i++) s += f[i] * f[i];
#pragma unroll
  for (int off = 32; off; off >>= 1) s += __shfl_down(s, off);
  __shared__ float wsum[4];
  __shared__ float rtot;
  if ((tid & 63) == 0) wsum[tid >> 6] = s;
  __syncthreads();
  if (tid == 0)
    rtot = rsqrtf((wsum[0] + wsum[1] + wsum[2] + wsum[3]) * (1.0f / DIM) + 1e-6f);
  __syncthreads();
  const float rms = rtot;
  if (isQ) {
    if (tid == 0) qscale[row] = rms;
    return;
  }
  ushort r[8];
#pragma unroll
  for (int i = 0; i < 8; i++) r[i] = f2b(f[i] * rms);
  *(uint4*)(kb + (size_t)(row - L_SEQ) * DIM + tid * 8) = *(uint4*)r;
}

// ======================= 256x256 8-wave 4-phase GEMM (round-7 schedule) ==========
template <int OUT_MODE>
__global__ __launch_bounds__(512, 2) void k_gemm256(const ushort* __restrict__ A,
                                                    const ushort* __restrict__ Bt,
                                                    const float* __restrict__ bias,
                                                    void* __restrict__ outp,
                                                    int M, int N, int K) {
  __shared__ __align__(16) ushort lds[65536];  // 128 KB
  const int tid = threadIdx.x;
  const int l = tid & 63, wid = tid >> 6;
  const int wm = wid >> 2, wn = wid & 3;
  const int lr = l & 15, lq = l >> 4;

  const int nwg = gridDim.x * gridDim.y;
  const int bid = blockIdx.y * gridDim.x + blockIdx.x;
  const int swz = (bid & 7) * (nwg >> 3) + (bid >> 3);
  const int m0 = (swz / gridDim.x) * 256, n0 = (swz % gridDim.x) * 256;

  f32x4_t acc[8][4];
#pragma unroll
  for (int i = 0; i < 8; i++)
#pragma unroll
    for (int j = 0; j < 4; j++) acc[i][j] = f32x4_t{0.f, 0.f, 0.f, 0.f};

  const int srow = l >> 3;
  const int schunk = ((l & 7) ^ (srow & 7)) * 8;
  auto stage = [&](int buf, int tile, int mat, int h) {
    const ushort* gp = mat ? Bt : A;
    const int rn0 = mat ? n0 : m0;
    const size_t r0 = (size_t)(rn0 + h * 128 + wid * 8 + srow);
    const ushort* g0 = gp + r0 * K + tile * 64 + schunk;
    ushort* l0 = &lds[buf * 32768 + mat * 16384 + (h * 128 + wid * 8) * 64];
    gll16(g0, l0);
    gll16(g0 + (size_t)64 * K, l0 + 64 * 64);
  };

  auto rdA = [&](int buf, int mf, int ks) -> bf16x8 {
    const int R = wm * 128 + mf * 16 + lr;
    return *(const bf16x8*)(&lds[buf * 32768 + R * 64 + (((ks * 4 + lq) ^ (R & 7)) * 8)]);
  };
  auto rdB = [&](int buf, int nf, int ks) -> bf16x8 {
    const int R = wn * 64 + nf * 16 + lr;
    return *(const bf16x8*)(&lds[buf * 32768 + 16384 + R * 64 + (((ks * 4 + lq) ^ (R & 7)) * 8)]);
  };

  const int NT = K >> 6;
  stage(0, 0, 0, 0); stage(0, 0, 0, 1); stage(0, 0, 1, 0); stage(0, 0, 1, 1);

  bf16x8 a[4][2], a2[4][2], b[2][2], b2[2][2];
  for (int kt = 0; kt < NT; kt++) {
    const int cur = kt & 1, nxt = cur ^ 1;
    const bool pf = (kt + 1 < NT);
    if (pf) { stage(nxt, kt + 1, 0, 0); asm volatile("s_waitcnt vmcnt(2)" ::: "memory"); }
    else    { asm volatile("s_waitcnt vmcnt(0)" ::: "memory"); }
    __builtin_amdgcn_sched_barrier(0);
    __builtin_amdgcn_s_barrier();
    __builtin_amdgcn_sched_barrier(0);
#pragma unroll
    for (int mf = 0; mf < 4; mf++) { a[mf][0] = rdA(cur, mf, 0); a[mf][1] = rdA(cur, mf, 1); }
#pragma unroll
    for (int nf = 0; nf < 2; nf++) { b[nf][0] = rdB(cur, nf, 0); b[nf][1] = rdB(cur, nf, 1); }
    __builtin_amdgcn_s_setprio(1);
#pragma unroll
    for (int mf = 0; mf < 4; mf++)
#pragma unroll
      for (int nf = 0; nf < 2; nf++) {
        acc[mf][nf] = __builtin_amdgcn_mfma_f32_16x16x32_bf16(a[mf][0], b[nf][0], acc[mf][nf], 0, 0, 0);
        acc[mf][nf] = __builtin_amdgcn_mfma_f32_16x16x32_bf16(a[mf][1], b[nf][1], acc[mf][nf], 0, 0, 0);
      }
    __builtin_amdgcn_s_setprio(0);
    __builtin_amdgcn_sched_barrier(0);
    __builtin_amdgcn_s_barrier();
    __builtin_amdgcn_sched_barrier(0);
#pragma unroll
    for (int mf = 0; mf < 4; mf++) { a2[mf][0] = rdA(cur, mf + 4, 0); a2[mf][1] = rdA(cur, mf + 4, 1); }
    if (pf) stage(nxt, kt + 1, 0, 1);
    __builtin_amdgcn_sched_barrier(0);
    __builtin_amdgcn_s_barrier();
    __builtin_amdgcn_sched_barrier(0);
    __builtin_amdgcn_s_setprio(1);
#pragma unroll
    for (int mf = 0; mf < 4; mf++)
#pragma unroll
      for (int nf = 0; nf < 2; nf++) {
        acc[mf + 4][nf] = __builtin_amdgcn_mfma_f32_16x16x32_bf16(a2[mf][0], b[nf][0], acc[mf + 4][nf], 0, 0, 0);
        acc[mf + 4][nf] = __builtin_amdgcn_mfma_f32_16x16x32_bf16(a2[mf][1], b[nf][1], acc[mf + 4][nf], 0, 0, 0);
      }
    __builtin_amdgcn_s_setprio(0);
    __builtin_amdgcn_sched_barrier(0);
    __builtin_amdgcn_s_barrier();
    __builtin_amdgcn_sched_barrier(0);
#pragma unroll
    for (int nf = 0; nf < 2; nf++) { b2[nf][0] = rdB(cur, nf + 2, 0); b2[nf][1] = rdB(cur, nf + 2, 1); }
    if (pf) stage(nxt, kt + 1, 1, 0);
    __builtin_amdgcn_sched_barrier(0);
    __builtin_amdgcn_s_barrier();
    __builtin_amdgcn_sched_barrier(0);
    __builtin_amdgcn_s_setprio(1);
#pragma unroll
    for (int mf = 0; mf < 4; mf++)
#pragma unroll
      for (int nf = 0; nf < 2; nf++) {
        acc[mf + 4][nf + 2] = __builtin_amdgcn_mfma_f32_16x16x32_bf16(a2[mf][0], b2[nf][0], acc[mf + 4][nf + 2], 0, 0, 0);
        acc[mf + 4][nf + 2] = __builtin_amdgcn_mfma_f32_16x16x32_bf16(a2[mf][1], b2[nf][1], acc[mf + 4][nf + 2], 0, 0, 0);
      }
    __builtin_amdgcn_s_setprio(0);
    __builtin_amdgcn_sched_barrier(0);
    __builtin_amdgcn_s_barrier();
    __builtin_amdgcn_sched_barrier(0);
#pragma unroll
    for (int mf = 0; mf < 4; mf++) { a[mf][0] = rdA(cur, mf, 0); a[mf][1] = rdA(cur, mf, 1); }
    if (pf) stage(nxt, kt + 1, 1, 1);
    __builtin_amdgcn_sched_barrier(0);
    __builtin_amdgcn_s_barrier();
    __builtin_amdgcn_sched_barrier(0);
    __builtin_amdgcn_s_setprio(1);
#pragma unroll
    for (int mf = 0; mf < 4; mf++)
#pragma unroll
      for (int nf = 0; nf < 2; nf++) {
        acc[mf][nf + 2] = __builtin_amdgcn_mfma_f32_16x16x32_bf16(a[mf][0], b2[nf][0], acc[mf][nf + 2], 0, 0, 0);
        acc[mf][nf + 2] = __builtin_amdgcn_mfma_f32_16x16x32_bf16(a[mf][1], b2[nf][1], acc[mf][nf + 2], 0, 0, 0);
      }
    __builtin_amdgcn_s_setprio(0);
    __builtin_amdgcn_sched_barrier(0);
    __builtin_amdgcn_s_barrier();
    __builtin_amdgcn_sched_barrier(0);
  }

#pragma unroll
  for (int nf = 0; nf < 4; nf++) {
    const int col = n0 + wn * 64 + nf * 16 + lr;
    const float bv = bias[col];
#pragma unroll
    for (int mf = 0; mf < 8; mf++) {
#pragma unroll
      for (int r = 0; r < 4; r++) {
        const int row = m0 + wm * 128 + mf * 16 + lq * 4 + r;
        const float v = acc[mf][nf][r] + bv;
        if constexpr (OUT_MODE == 0)
          ((float*)outp)[(size_t)row * N + col] = v;
        else
          ((ushort*)outp)[(size_t)row * N + col] = f2b(v);
      }
    }
  }
}

// ============ KV projection GEMM: M=512, N=4096, K=4096, depth-4 pipeline ============
__global__ __launch_bounds__(256) void k_gemmkv(const ushort* __restrict__ A,
                                                const ushort* __restrict__ Bt,
                                                const float* __restrict__ biasK,
                                                const float* __restrict__ biasV,
                                                ushort* __restrict__ outK,
                                                ushort* __restrict__ outVt) {
  __shared__ __align__(16) ushort As[4][128 * 32];  // 32 KB
  __shared__ __align__(16) ushort Bs[4][64 * 32];   // 16 KB
  const int tid = threadIdx.x;
  const int l = tid & 63, wid = tid >> 6;
  const int wr = wid >> 1, wc = wid & 1;
  const int lr = l & 15, lq = l >> 4;
  const int K = CTX, M = S_SEQ;

  const int bid = blockIdx.x;                 // grid = 256
  const int swz = (bid & 7) * 32 + (bid >> 3);
  const int n0 = (swz >> 2) * 64, m0 = (swz & 3) * 128;

  f32x4_t acc[4][2];
#pragma unroll
  for (int i = 0; i < 4; i++)
#pragma unroll
    for (int j = 0; j < 2; j++) acc[i][j] = f32x4_t{0.f, 0.f, 0.f, 0.f};

  const int srow = l >> 2;
  const int schunk = ((l & 3) ^ ((srow >> 1) & 3)) * 8;
  const ushort* gA = A  + (size_t)(m0 + srow) * K + schunk;
  const ushort* gB = Bt + (size_t)(n0 + wid * 16 + srow) * K + schunk;

  auto stage = [&](int buf, int kt) {
    const int ko = kt * 32;
    gll16(gA + (size_t)(wid * 16) * K + ko,      &As[buf][(wid * 16) * 32]);
    gll16(gA + (size_t)(64 + wid * 16) * K + ko, &As[buf][(64 + wid * 16) * 32]);
    gll16(gB + ko,                               &Bs[buf][(wid * 16) * 32]);
  };
  auto rdA = [&](int buf, int mi) -> bf16x8 {
    const int R = wr * 64 + mi * 16 + lr;
    return *(const bf16x8*)(&As[buf][R * 32 + ((lq ^ ((R >> 1) & 3)) * 8)]);
  };
  auto rdB = [&](int buf, int ni) -> bf16x8 {
    const int R = wc * 32 + ni * 16 + lr;
    return *(const bf16x8*)(&Bs[buf][R * 32 + ((lq ^ ((R >> 1) & 3)) * 8)]);
  };

  const int NT = K >> 5;  // 128
  stage(0, 0); stage(1, 1); stage(2, 2);
  for (int t = 0; t < NT; t++) {
    const int cur = t & 3;
    if (t + 3 < NT) { stage((t + 3) & 3, t + 3); asm volatile("s_waitcnt vmcnt(9)" ::: "memory"); }
    else if (t + 2 < NT) { asm volatile("s_waitcnt vmcnt(6)" ::: "memory"); }
    else if (t + 1 < NT) { asm volatile("s_waitcnt vmcnt(3)" ::: "memory"); }
    else                 { asm volatile("s_waitcnt vmcnt(0)" ::: "memory"); }
    __builtin_amdgcn_sched_barrier(0);
    __builtin_amdgcn_s_barrier();
    __builtin_amdgcn_sched_barrier(0);

    bf16x8 af[4], bfr[2];
#pragma unroll
    for (int mi = 0; mi < 4; mi++) af[mi] = rdA(cur, mi);
#pragma unroll
    for (int ni = 0; ni < 2; ni++) bfr[ni] = rdB(cur, ni);
    __builtin_amdgcn_s_setprio(1);
#pragma unroll
    for (int mi = 0; mi < 4; mi++)
#pragma unroll
      for (int ni = 0; ni < 2; ni++)
        acc[mi][ni] = __builtin_amdgcn_mfma_f32_16x16x32_bf16(af[mi], bfr[ni], acc[mi][ni], 0, 0, 0);
    __builtin_amdgcn_s_setprio(0);
    __builtin_amdgcn_sched_barrier(0);
    __builtin_amdgcn_s_barrier();
    __builtin_amdgcn_sched_barrier(0);
  }

#pragma unroll
  for (int mi = 0; mi < 4; mi++) {
#pragma unroll
    for (int ni = 0; ni < 2; ni++) {
      const int col = n0 + wc * 32 + ni * 16 + lr;
      const float bv = (col < DIM) ? biasK[col] : biasV[col - DIM];
#pragma unroll
      for (int r = 0; r < 4; r++) {
        const int row = m0 + wr * 64 + mi * 16 + lq * 4 + r;
        const float v = acc[mi][ni][r] + bv;
        if (col < DIM) outK[(size_t)row * DIM + col] = f2b(v);
        else           outVt[(size_t)(col - DIM) * M + row] = f2b(v);  // V^T
      }
    }
  }
}

// ============ Flash attention, swapped-operand 32x32x16 ============
// Q read from qraw with qscale[row] * G[d] folded into the once-per-block
// fragment prep (rms_q, g_q, g_k, 1/sqrt(128) all in there).
__global__ __launch_bounds__(256) void k_attn(const ushort* __restrict__ Qraw,
                                              const ushort* __restrict__ Kb,
                                              const ushort* __restrict__ Vt,
                                              const float* __restrict__ qscale,
                                              const float* __restrict__ g2,
                                              ushort* __restrict__ Ob) {
  __shared__ __align__(16) ushort smem[16384];  // 32KB: Ks [64][128] + Vs [128][64]
  ushort* Ks = smem;
  ushort* Vs = smem + 64 * 128;

  const int tid = threadIdx.x;
  const int l = tid & 63, wid = tid >> 6;
  const int lo = l & 31, hi = l >> 5;

  const int bid = blockIdx.x;                  // grid = 1024
  const int swz = (bid & 7) * 128 + (bid >> 3);
  const int h = swz >> 6;
  const int q0 = (swz & 63) * 128 + wid * 32;

  // Q fragments with qscale*G folded in
  bf16x8 qf[8];
  {
    const float qs = qscale[q0 + lo];
    const ushort* qp = Qraw + (size_t)(q0 + lo) * DIM + h * HD + hi * 8;
    const float* gp = g2 + h * HD + hi * 8;
#pragma unroll
    for (int ds = 0; ds < 8; ds++) {
      union { uint4 u; ushort us[8]; } rw;
      rw.u = *(const uint4*)(qp + ds * 16);
      const float* gg = gp + ds * 16;
      union { uint32_t w[4]; bf16x8 v; } ov;
#pragma unroll
      for (int j = 0; j < 4; j++)
        ov.w[j] = pk2(b2f(rw.us[2 * j]) * qs * gg[2 * j],
                      b2f(rw.us[2 * j + 1]) * qs * gg[2 * j + 1]);
      qf[ds] = ov.v;
    }
  }

  f32x16_t o[4] = {};          // O^T: lane q = lo, d = nt*32 + crow(r,hi)
  float m_run = -1e30f, l_run = 0.f;

  for (int kvb = 0; kvb < S_SEQ / 64; kvb++) {
    __syncthreads();
#pragma unroll
    for (int i = 0; i < 4; i++) {
      const int c = i * 256 + tid, row = c >> 4, cs = c & 15;
      gll16(Kb + (size_t)(kvb * 64 + row) * DIM + h * HD + ((cs ^ (row & 7)) * 8),
            Ks + c * 8);
    }
#pragma unroll
    for (int i = 0; i < 4; i++) {
      const int c = i * 256 + tid, row = c >> 3, cs = c & 7;
      gll16(Vt + (size_t)(h * HD + row) * S_SEQ + kvb * 64 + ((cs ^ (row & 7)) * 8),
            Vs + c * 8);
    }
    __syncthreads();

    f32x16_t sA = {}, sB = {};
#pragma unroll
    for (int ds = 0; ds < 8; ds++) {
      const int ch = ((hi + ds * 2) ^ (lo & 7)) * 8;
      bf16x8 kA = *(const bf16x8*)(Ks + lo * 128 + ch);
      bf16x8 kB = *(const bf16x8*)(Ks + (32 + lo) * 128 + ch);
      sA = __builtin_amdgcn_mfma_f32_32x32x16_bf16(kA, qf[ds], sA, 0, 0, 0);
      sB = __builtin_amdgcn_mfma_f32_32x32x16_bf16(kB, qf[ds], sB, 0, 0, 0);
    }

    float p[32];
#pragma unroll
    for (int i = 0; i < 16; i++) { p[i] = sA[i]; p[16 + i] = sB[i]; }
    float pm = p[0];
#pragma unroll
    for (int i = 1; i < 32; i++) pm = fmaxf(pm, p[i]);
    pm = fmaxf(pm, __shfl_xor(pm, 32));
    const float mn = fmaxf(m_run, pm);
    const float corr = __expf(m_run - mn);
    m_run = mn;
    float ps = 0.f;
#pragma unroll
    for (int i = 0; i < 32; i++) { p[i] = __expf(p[i] - mn); ps += p[i]; }
    ps += __shfl_xor(ps, 32);
    l_run = l_run * corr + ps;
#pragma unroll
    for (int nt = 0; nt < 4; nt++) o[nt] *= corr;

    uint32_t c[16];
#pragma unroll
    for (int j = 0; j < 16; j++) c[j] = pk2(p[2 * j], p[2 * j + 1]);
    bf16x8 pf[4];
#pragma unroll
    for (int s = 0; s < 4; s++) {
      const uint32_t ca = c[4 * s], cb = c[4 * s + 1], cc = c[4 * s + 2], cd = c[4 * s + 3];
      const uint32_t sa = __shfl_xor(ca, 32), sb = __shfl_xor(cb, 32);
      const uint32_t sc = __shfl_xor(cc, 32), sd = __shfl_xor(cd, 32);
      union { uint32_t u[4]; bf16x8 v; } f;
      f.u[0] = hi ? sc : ca; f.u[1] = hi ? sd : cb;
      f.u[2] = hi ? cc : sa; f.u[3] = hi ? cd : sb;
      pf[s] = f.v;
    }

#pragma unroll
    for (int nt = 0; nt < 4; nt++) {
      const int vrow = nt * 32 + lo;
#pragma unroll
      for (int s = 0; s < 4; s++) {
        bf16x8 vf = *(const bf16x8*)(Vs + vrow * 64 + (((s * 2 + hi) ^ (lo & 7)) * 8));
        o[nt] = __builtin_amdgcn_mfma_f32_32x32x16_bf16(vf, pf[s], o[nt], 0, 0, 0);
      }
    }
  }

  const float inv = 1.0f / l_run;
#pragma unroll
  for (int nt = 0; nt < 4; nt++) o[nt] *= inv;

  __syncthreads();
  float* tb = (float*)smem + wid * (32 * 33);
  const int q2 = l >> 1, dh = (l & 1) * 16;
#pragma unroll
  for (int nt = 0; nt < 4; nt++) {
#pragma unroll
    for (int r = 0; r < 16; r++)
      tb[lo * 33 + ((r & 3) + 8 * (r >> 2) + 4 * hi)] = o[nt][r];
    asm volatile("s_waitcnt lgkmcnt(0)" ::: "memory");
    __builtin_amdgcn_sched_barrier(0);
    ushort tmp[16];
#pragma unroll
    for (int j = 0; j < 16; j++) tmp[j] = f2b(tb[q2 * 33 + dh + j]);
    asm volatile("s_waitcnt lgkmcnt(0)" ::: "memory");
    __builtin_amdgcn_sched_barrier(0);
    const size_t oaddr = (size_t)(q0 + q2) * DIM + h * HD + nt * 32 + dh;
    *(uint4*)(Ob + oaddr) = *(uint4*)tmp;
    *(uint4*)(Ob + oaddr + 8) = *(uint4*)(tmp + 8);
  }
}

extern "C" void kernel_launch(void* const* d_in, const int* in_sizes, int n_in,
                              void* d_out, int out_size, void* d_ws, size_t ws_size,
                              hipStream_t stream) {
  const float* x   = (const float*)d_in[0];
  const float* ctx = (const float*)d_in[1];
  const float* Wq  = (const float*)d_in[2];
  const float* bq  = (const float*)d_in[3];
  const float* Wk  = (const float*)d_in[4];
  const float* bk  = (const float*)d_in[5];
  const float* Wv  = (const float*)d_in[6];
  const float* bv  = (const float*)d_in[7];
  const float* Wo  = (const float*)d_in[8];
  const float* bo  = (const float*)d_in[9];
  const float* gq  = (const float*)d_in[10];
  const float* gk  = (const float*)d_in[11];

  char* ws = (char*)d_ws;
  ushort* wqt    = (ushort*)(ws);                 // [2048][2048] bf16   8.39MB
  ushort* wkt    = (ushort*)(ws + 8388608);       // [2048][4096] bf16  16.78MB } adjacent =>
  ushort* wvt    = (ushort*)(ws + 25165824);      // [2048][4096] bf16  16.78MB } [4096][4096] KV
  ushort* wot    = (ushort*)(ws + 41943040);      // [2048][2048] bf16   8.39MB
  ushort* ctxb   = (ushort*)(ws + 50331648);      // [512][4096]  bf16   4.19MB
  float*  qscale = (float*)(ws + 54525952);       // [8192] f32  32KB
  float*  g2     = (float*)(ws + 54558720);       // [2048] f32   8KB
  ushort* kb     = (ushort*)(ws + 83886080);      // [512][2048]  bf16   2.10MB (rms-normalized K)
  ushort* vt     = (ushort*)(ws + 85983232);      // [2048][512]  bf16   2.10MB (V^T per-head)
  ushort* xb     = (ushort*)(ws + 88080384);      // [8192][2048] bf16  33.55MB (x cast)
  ushort* kraw   = (ushort*)(ws + 88080384);      // [512][2048]  bf16   2.10MB (aliases xb; xb dead after Qproj)
  ushort* attnb  = (ushort*)(ws + 88080384);      // [8192][2048] bf16  33.55MB (aliases; kraw dead after qknorm)
  ushort* qraw   = (ushort*)(ws + 121634816);     // [8192][2048] bf16  33.55MB (pre-norm Q)

  // 1. preprocessing: casts + weight transposes + G = gq*gk/sqrt(HD)
  k_prep<<<33793, 256, 0, stream>>>(x, ctx, Wq, Wk, Wv, Wo, gq, gk,
                                    xb, ctxb, wqt, wkt, wvt, wot, g2);
  // 2. Q projection: qraw = x@Wq + bq (bf16)
  k_gemm256<1><<<dim3(DIM / 256, L_SEQ / 256), 512, 0, stream>>>(xb, wqt, bq, qraw, L_SEQ, DIM, DIM);
  // 3. fused K+V projection (kraw overwrites dead xb)
  k_gemmkv<<<256, 256, 0, stream>>>(ctxb, wkt, bk, bv, kraw, vt);
  // 4. Q row scales + K rms-normalize
  k_qknorm<<<L_SEQ + S_SEQ, 256, 0, stream>>>(qraw, kraw, qscale, kb);
  // 5. attention (qscale*G folded into Q-frag prep)
  k_attn<<<L_SEQ / 128 * NH, 256, 0, stream>>>(qraw, kb, vt, qscale, g2, attnb);
  // 6. out = attn @ Wo + bo (fp32)
  k_gemm256<0><<<dim3(DIM / 256, L_SEQ / 256), 512, 0, stream>>>(attnb, wot, bo, d_out, L_SEQ, DIM, DIM);
}

// Round 12
// 315.327 us; speedup vs baseline: 2.1052x; 1.0114x over previous
//
#include <hip/hip_runtime.h>
#include <hip/hip_bf16.h>
#include <stdint.h>

#define L_SEQ 8192
#define S_SEQ 512
#define DIM   2048
#define CTX   4096
#define NH    16
#define HD    128

typedef __bf16 bf16_t;
typedef bf16_t bf16x8 __attribute__((ext_vector_type(8)));
typedef float  f32x4_t __attribute__((ext_vector_type(4)));
typedef float  f32x16_t __attribute__((ext_vector_type(16)));

__device__ __forceinline__ ushort f2b(float f) {
  bf16_t h = (bf16_t)f;                     // RNE; compiler can pair into v_cvt_pk_bf16_f32
  return __builtin_bit_cast(ushort, h);
}
__device__ __forceinline__ uint32_t pk2(float a, float b) {
  return (uint32_t)f2b(a) | ((uint32_t)f2b(b) << 16);
}
__device__ __forceinline__ float b2f(ushort u) {
  union { uint32_t u; float f; } v; v.u = ((uint32_t)u) << 16;
  return v.f;
}
__device__ __forceinline__ void gll16(const ushort* g, ushort* l) {
  __builtin_amdgcn_global_load_lds((const __attribute__((address_space(1))) void*)g,
                                   (__attribute__((address_space(3))) void*)l, 16, 0, 0);
}

// ============ fused preprocessing: x/ctx casts + 4 weight transposes + G ============
__global__ __launch_bounds__(256) void k_prep(const float* __restrict__ x,
                                              const float* __restrict__ ctx,
                                              const float* __restrict__ Wq,
                                              const float* __restrict__ Wk,
                                              const float* __restrict__ Wv,
                                              const float* __restrict__ Wo,
                                              const float* __restrict__ gq,
                                              const float* __restrict__ gk,
                                              ushort* __restrict__ xb,
                                              ushort* __restrict__ ctxb,
                                              ushort* __restrict__ wqt,
                                              ushort* __restrict__ wkt,
                                              ushort* __restrict__ wvt,
                                              ushort* __restrict__ wot,
                                              float* __restrict__ g2) {
  const int b = blockIdx.x;
  const int tid = threadIdx.x;
  if (b == 33792) {  // G = gq*gk/sqrt(HD)
    const int d = tid * 8;
#pragma unroll
    for (int j = 0; j < 8; j++) g2[d + j] = gq[d + j] * gk[d + j] * 0.08838834764831843f;
    return;
  }
  if (b < 9216) {  // elementwise casts
    const float* src; ushort* dst; size_t i;
    if (b < 8192) { src = x;   dst = xb;   i = ((size_t)b * 256 + tid) * 8; }
    else          { src = ctx; dst = ctxb; i = ((size_t)(b - 8192) * 256 + tid) * 8; }
    float4 a = *(const float4*)(src + i);
    float4 c = *(const float4*)(src + i + 4);
    uint4 r;
    r.x = pk2(a.x, a.y); r.y = pk2(a.z, a.w);
    r.z = pk2(c.x, c.y); r.w = pk2(c.z, c.w);
    *(uint4*)(dst + i) = r;
    return;
  }
  // transpose + cast fp32 [K][2048] -> bf16 [2048][K]
  __shared__ float t[32][33];
  const float* src; ushort* dst; int K, ti;
  if (b < 13312)      { src = Wq; dst = wqt; K = DIM; ti = b - 9216; }
  else if (b < 21504) { src = Wk; dst = wkt; K = CTX; ti = b - 13312; }
  else if (b < 29696) { src = Wv; dst = wvt; K = CTX; ti = b - 21504; }
  else                { src = Wo; dst = wot; K = DIM; ti = b - 29696; }
  const int n0 = (ti & 63) * 32, k0 = (ti >> 6) * 32;
  const int tx = tid & 31, ty = tid >> 5;
#pragma unroll
  for (int i = 0; i < 4; i++)
    t[ty + 8 * i][tx] = src[(size_t)(k0 + ty + 8 * i) * DIM + n0 + tx];
  __syncthreads();
#pragma unroll
  for (int i = 0; i < 4; i++)
    dst[(size_t)(n0 + ty + 8 * i) * K + k0 + tx] = f2b(t[tx][ty + 8 * i]);
}

// ============ K rms-normalize (512 rows) ============
__global__ __launch_bounds__(256) void k_knorm(const ushort* __restrict__ kraw,
                                               ushort* __restrict__ kb) {
  const int row = blockIdx.x, tid = threadIdx.x;
  uint4 v = *(const uint4*)(kraw + (size_t)row * DIM + tid * 8);
  const uint32_t* vu = (const uint32_t*)&v;
  float f[8];
#pragma unroll
  for (int i = 0; i < 4; i++) {
    f[2 * i]     = b2f((ushort)(vu[i] & 0xffffu));
    f[2 * i + 1] = b2f((ushort)(vu[i] >> 16));
  }
  float s = 0.f;
#pragma unroll
  for (int i = 0; i < 8; i++) s += f[i] * f[i];
#pragma unroll
  for (int off = 32; off; off >>= 1) s += __shfl_down(s, off);
  __shared__ float wsum[4];
  __shared__ float rtot;
  if ((tid & 63) == 0) wsum[tid >> 6] = s;
  __syncthreads();
  if (tid == 0)
    rtot = rsqrtf((wsum[0] + wsum[1] + wsum[2] + wsum[3]) * (1.0f / DIM) + 1e-6f);
  __syncthreads();
  const float rms = rtot;
  ushort r[8];
#pragma unroll
  for (int i = 0; i < 8; i++) r[i] = f2b(f[i] * rms);
  *(uint4*)(kb + (size_t)row * DIM + tid * 8) = *(uint4*)r;
}

// ======================= 256x256 8-wave 4-phase GEMM (round-7 schedule) ==========
// OUT_MODE 1 additionally writes per-row partial sum-of-squares (over this
// block's 256 cols, fp32 incl. bias) to qpart[row*32 + (n0>>8)*4 + wn] — one
// writer per slot, deterministic (no atomics). attn derives rms_q from these.
template <int OUT_MODE>
__global__ __launch_bounds__(512, 2) void k_gemm256(const ushort* __restrict__ A,
                                                    const ushort* __restrict__ Bt,
                                                    const float* __restrict__ bias,
                                                    void* __restrict__ outp,
                                                    float* __restrict__ qpart,
                                                    int M, int N, int K) {
  __shared__ __align__(16) ushort lds[65536];  // 128 KB
  const int tid = threadIdx.x;
  const int l = tid & 63, wid = tid >> 6;
  const int wm = wid >> 2, wn = wid & 3;
  const int lr = l & 15, lq = l >> 4;

  const int nwg = gridDim.x * gridDim.y;
  const int bid = blockIdx.y * gridDim.x + blockIdx.x;
  const int swz = (bid & 7) * (nwg >> 3) + (bid >> 3);
  const int m0 = (swz / gridDim.x) * 256, n0 = (swz % gridDim.x) * 256;

  f32x4_t acc[8][4];
#pragma unroll
  for (int i = 0; i < 8; i++)
#pragma unroll
    for (int j = 0; j < 4; j++) acc[i][j] = f32x4_t{0.f, 0.f, 0.f, 0.f};

  const int srow = l >> 3;
  const int schunk = ((l & 7) ^ (srow & 7)) * 8;
  auto stage = [&](int buf, int tile, int mat, int h) {
    const ushort* gp = mat ? Bt : A;
    const int rn0 = mat ? n0 : m0;
    const size_t r0 = (size_t)(rn0 + h * 128 + wid * 8 + srow);
    const ushort* g0 = gp + r0 * K + tile * 64 + schunk;
    ushort* l0 = &lds[buf * 32768 + mat * 16384 + (h * 128 + wid * 8) * 64];
    gll16(g0, l0);
    gll16(g0 + (size_t)64 * K, l0 + 64 * 64);
  };

  auto rdA = [&](int buf, int mf, int ks) -> bf16x8 {
    const int R = wm * 128 + mf * 16 + lr;
    return *(const bf16x8*)(&lds[buf * 32768 + R * 64 + (((ks * 4 + lq) ^ (R & 7)) * 8)]);
  };
  auto rdB = [&](int buf, int nf, int ks) -> bf16x8 {
    const int R = wn * 64 + nf * 16 + lr;
    return *(const bf16x8*)(&lds[buf * 32768 + 16384 + R * 64 + (((ks * 4 + lq) ^ (R & 7)) * 8)]);
  };

  const int NT = K >> 6;
  stage(0, 0, 0, 0); stage(0, 0, 0, 1); stage(0, 0, 1, 0); stage(0, 0, 1, 1);

  bf16x8 a[4][2], a2[4][2], b[2][2], b2[2][2];
  for (int kt = 0; kt < NT; kt++) {
    const int cur = kt & 1, nxt = cur ^ 1;
    const bool pf = (kt + 1 < NT);
    if (pf) { stage(nxt, kt + 1, 0, 0); asm volatile("s_waitcnt vmcnt(2)" ::: "memory"); }
    else    { asm volatile("s_waitcnt vmcnt(0)" ::: "memory"); }
    __builtin_amdgcn_sched_barrier(0);
    __builtin_amdgcn_s_barrier();
    __builtin_amdgcn_sched_barrier(0);
#pragma unroll
    for (int mf = 0; mf < 4; mf++) { a[mf][0] = rdA(cur, mf, 0); a[mf][1] = rdA(cur, mf, 1); }
#pragma unroll
    for (int nf = 0; nf < 2; nf++) { b[nf][0] = rdB(cur, nf, 0); b[nf][1] = rdB(cur, nf, 1); }
    __builtin_amdgcn_s_setprio(1);
#pragma unroll
    for (int mf = 0; mf < 4; mf++)
#pragma unroll
      for (int nf = 0; nf < 2; nf++) {
        acc[mf][nf] = __builtin_amdgcn_mfma_f32_16x16x32_bf16(a[mf][0], b[nf][0], acc[mf][nf], 0, 0, 0);
        acc[mf][nf] = __builtin_amdgcn_mfma_f32_16x16x32_bf16(a[mf][1], b[nf][1], acc[mf][nf], 0, 0, 0);
      }
    __builtin_amdgcn_s_setprio(0);
    __builtin_amdgcn_sched_barrier(0);
    __builtin_amdgcn_s_barrier();
    __builtin_amdgcn_sched_barrier(0);
#pragma unroll
    for (int mf = 0; mf < 4; mf++) { a2[mf][0] = rdA(cur, mf + 4, 0); a2[mf][1] = rdA(cur, mf + 4, 1); }
    if (pf) stage(nxt, kt + 1, 0, 1);
    __builtin_amdgcn_sched_barrier(0);
    __builtin_amdgcn_s_barrier();
    __builtin_amdgcn_sched_barrier(0);
    __builtin_amdgcn_s_setprio(1);
#pragma unroll
    for (int mf = 0; mf < 4; mf++)
#pragma unroll
      for (int nf = 0; nf < 2; nf++) {
        acc[mf + 4][nf] = __builtin_amdgcn_mfma_f32_16x16x32_bf16(a2[mf][0], b[nf][0], acc[mf + 4][nf], 0, 0, 0);
        acc[mf + 4][nf] = __builtin_amdgcn_mfma_f32_16x16x32_bf16(a2[mf][1], b[nf][1], acc[mf + 4][nf], 0, 0, 0);
      }
    __builtin_amdgcn_s_setprio(0);
    __builtin_amdgcn_sched_barrier(0);
    __builtin_amdgcn_s_barrier();
    __builtin_amdgcn_sched_barrier(0);
#pragma unroll
    for (int nf = 0; nf < 2; nf++) { b2[nf][0] = rdB(cur, nf + 2, 0); b2[nf][1] = rdB(cur, nf + 2, 1); }
    if (pf) stage(nxt, kt + 1, 1, 0);
    __builtin_amdgcn_sched_barrier(0);
    __builtin_amdgcn_s_barrier();
    __builtin_amdgcn_sched_barrier(0);
    __builtin_amdgcn_s_setprio(1);
#pragma unroll
    for (int mf = 0; mf < 4; mf++)
#pragma unroll
      for (int nf = 0; nf < 2; nf++) {
        acc[mf + 4][nf + 2] = __builtin_amdgcn_mfma_f32_16x16x32_bf16(a2[mf][0], b2[nf][0], acc[mf + 4][nf + 2], 0, 0, 0);
        acc[mf + 4][nf + 2] = __builtin_amdgcn_mfma_f32_16x16x32_bf16(a2[mf][1], b2[nf][1], acc[mf + 4][nf + 2], 0, 0, 0);
      }
    __builtin_amdgcn_s_setprio(0);
    __builtin_amdgcn_sched_barrier(0);
    __builtin_amdgcn_s_barrier();
    __builtin_amdgcn_sched_barrier(0);
#pragma unroll
    for (int mf = 0; mf < 4; mf++) { a[mf][0] = rdA(cur, mf, 0); a[mf][1] = rdA(cur, mf, 1); }
    if (pf) stage(nxt, kt + 1, 1, 1);
    __builtin_amdgcn_sched_barrier(0);
    __builtin_amdgcn_s_barrier();
    __builtin_amdgcn_sched_barrier(0);
    __builtin_amdgcn_s_setprio(1);
#pragma unroll
    for (int mf = 0; mf < 4; mf++)
#pragma unroll
      for (int nf = 0; nf < 2; nf++) {
        acc[mf][nf + 2] = __builtin_amdgcn_mfma_f32_16x16x32_bf16(a[mf][0], b2[nf][0], acc[mf][nf + 2], 0, 0, 0);
        acc[mf][nf + 2] = __builtin_amdgcn_mfma_f32_16x16x32_bf16(a[mf][1], b2[nf][1], acc[mf][nf + 2], 0, 0, 0);
      }
    __builtin_amdgcn_s_setprio(0);
    __builtin_amdgcn_sched_barrier(0);
    __builtin_amdgcn_s_barrier();
    __builtin_amdgcn_sched_barrier(0);
  }

  // ---- epilogue ----
  float bvs[4];
#pragma unroll
  for (int nf = 0; nf < 4; nf++) bvs[nf] = bias[n0 + wn * 64 + nf * 16 + lr];
#pragma unroll
  for (int nf = 0; nf < 4; nf++) {
    const int col = n0 + wn * 64 + nf * 16 + lr;
#pragma unroll
    for (int mf = 0; mf < 8; mf++) {
#pragma unroll
      for (int r = 0; r < 4; r++) {
        const int row = m0 + wm * 128 + mf * 16 + lq * 4 + r;
        const float v = acc[mf][nf][r] + bvs[nf];
        if constexpr (OUT_MODE == 0)
          ((float*)outp)[(size_t)row * N + col] = v;
        else
          ((ushort*)outp)[(size_t)row * N + col] = f2b(v);
      }
    }
  }
  if constexpr (OUT_MODE == 1) {
    // per-row partial sum of squares over this block's 256 cols (fp32, incl bias)
    const int slot = (n0 >> 8) * 4 + wn;
#pragma unroll
    for (int mf = 0; mf < 8; mf++) {
#pragma unroll
      for (int r = 0; r < 4; r++) {
        float s = 0.f;
#pragma unroll
        for (int nf = 0; nf < 4; nf++) {
          const float v = acc[mf][nf][r] + bvs[nf];
          s += v * v;
        }
        s += __shfl_xor(s, 1); s += __shfl_xor(s, 2);
        s += __shfl_xor(s, 4); s += __shfl_xor(s, 8);
        if (lr == 0)
          qpart[(size_t)(m0 + wm * 128 + mf * 16 + lq * 4 + r) * 32 + slot] = s;
      }
    }
  }
}

// ============ KV projection GEMM: M=512, N=4096, K=4096, depth-4 pipeline ============
__global__ __launch_bounds__(256) void k_gemmkv(const ushort* __restrict__ A,
                                                const ushort* __restrict__ Bt,
                                                const float* __restrict__ biasK,
                                                const float* __restrict__ biasV,
                                                ushort* __restrict__ outK,
                                                ushort* __restrict__ outVt) {
  __shared__ __align__(16) ushort As[4][128 * 32];  // 32 KB
  __shared__ __align__(16) ushort Bs[4][64 * 32];   // 16 KB
  const int tid = threadIdx.x;
  const int l = tid & 63, wid = tid >> 6;
  const int wr = wid >> 1, wc = wid & 1;
  const int lr = l & 15, lq = l >> 4;
  const int K = CTX, M = S_SEQ;

  const int bid = blockIdx.x;                 // grid = 256
  const int swz = (bid & 7) * 32 + (bid >> 3);
  const int n0 = (swz >> 2) * 64, m0 = (swz & 3) * 128;

  f32x4_t acc[4][2];
#pragma unroll
  for (int i = 0; i < 4; i++)
#pragma unroll
    for (int j = 0; j < 2; j++) acc[i][j] = f32x4_t{0.f, 0.f, 0.f, 0.f};

  const int srow = l >> 2;
  const int schunk = ((l & 3) ^ ((srow >> 1) & 3)) * 8;
  const ushort* gA = A  + (size_t)(m0 + srow) * K + schunk;
  const ushort* gB = Bt + (size_t)(n0 + wid * 16 + srow) * K + schunk;

  auto stage = [&](int buf, int kt) {
    const int ko = kt * 32;
    gll16(gA + (size_t)(wid * 16) * K + ko,      &As[buf][(wid * 16) * 32]);
    gll16(gA + (size_t)(64 + wid * 16) * K + ko, &As[buf][(64 + wid * 16) * 32]);
    gll16(gB + ko,                               &Bs[buf][(wid * 16) * 32]);
  };
  auto rdA = [&](int buf, int mi) -> bf16x8 {
    const int R = wr * 64 + mi * 16 + lr;
    return *(const bf16x8*)(&As[buf][R * 32 + ((lq ^ ((R >> 1) & 3)) * 8)]);
  };
  auto rdB = [&](int buf, int ni) -> bf16x8 {
    const int R = wc * 32 + ni * 16 + lr;
    return *(const bf16x8*)(&Bs[buf][R * 32 + ((lq ^ ((R >> 1) & 3)) * 8)]);
  };

  const int NT = K >> 5;  // 128
  stage(0, 0); stage(1, 1); stage(2, 2);
  for (int t = 0; t < NT; t++) {
    const int cur = t & 3;
    if (t + 3 < NT) { stage((t + 3) & 3, t + 3); asm volatile("s_waitcnt vmcnt(9)" ::: "memory"); }
    else if (t + 2 < NT) { asm volatile("s_waitcnt vmcnt(6)" ::: "memory"); }
    else if (t + 1 < NT) { asm volatile("s_waitcnt vmcnt(3)" ::: "memory"); }
    else                 { asm volatile("s_waitcnt vmcnt(0)" ::: "memory"); }
    __builtin_amdgcn_sched_barrier(0);
    __builtin_amdgcn_s_barrier();
    __builtin_amdgcn_sched_barrier(0);

    bf16x8 af[4], bfr[2];
#pragma unroll
    for (int mi = 0; mi < 4; mi++) af[mi] = rdA(cur, mi);
#pragma unroll
    for (int ni = 0; ni < 2; ni++) bfr[ni] = rdB(cur, ni);
    __builtin_amdgcn_s_setprio(1);
#pragma unroll
    for (int mi = 0; mi < 4; mi++)
#pragma unroll
      for (int ni = 0; ni < 2; ni++)
        acc[mi][ni] = __builtin_amdgcn_mfma_f32_16x16x32_bf16(af[mi], bfr[ni], acc[mi][ni], 0, 0, 0);
    __builtin_amdgcn_s_setprio(0);
    __builtin_amdgcn_sched_barrier(0);
    __builtin_amdgcn_s_barrier();
    __builtin_amdgcn_sched_barrier(0);
  }

  if (n0 < DIM) {
    // K block: row-major bf16 writes
#pragma unroll
    for (int mi = 0; mi < 4; mi++) {
#pragma unroll
      for (int ni = 0; ni < 2; ni++) {
        const int col = n0 + wc * 32 + ni * 16 + lr;
        const float bv = biasK[col];
#pragma unroll
        for (int r = 0; r < 4; r++) {
          const int row = m0 + wr * 64 + mi * 16 + lq * 4 + r;
          outK[(size_t)row * DIM + col] = f2b(acc[mi][ni][r] + bv);
        }
      }
    }
  } else {
    // V block: transpose through LDS for coalesced V^T stores
    ushort* ldst = &As[0][0];  // [64 cols][128 rows] ushort = 16 KB (main loop done)
    __syncthreads();
#pragma unroll
    for (int mi = 0; mi < 4; mi++) {
#pragma unroll
      for (int ni = 0; ni < 2; ni++) {
        const int ccol = wc * 32 + ni * 16 + lr;
        const float bv = biasV[n0 - DIM + ccol];
#pragma unroll
        for (int r = 0; r < 4; r++) {
          const int crow = wr * 64 + mi * 16 + lq * 4 + r;
          ldst[ccol * 128 + crow] = f2b(acc[mi][ni][r] + bv);
        }
      }
    }
    __syncthreads();
    const int c = tid >> 2, j0 = (tid & 3) * 32;
    ushort* dst = outVt + (size_t)(n0 - DIM + c) * M + m0 + j0;
#pragma unroll
    for (int k2 = 0; k2 < 4; k2++)
      *(uint4*)(dst + k2 * 8) = *(const uint4*)(ldst + c * 128 + j0 + k2 * 8);
  }
}

// ============ Flash attention, swapped-operand 32x32x16 ============
// rms_q derived from qpart partial sums; qscale*G folded into Q-frag prep.
__global__ __launch_bounds__(256) void k_attn(const ushort* __restrict__ Qraw,
                                              const ushort* __restrict__ Kb,
                                              const ushort* __restrict__ Vt,
                                              const float* __restrict__ qpart,
                                              const float* __restrict__ g2,
                                              ushort* __restrict__ Ob) {
  __shared__ __align__(16) ushort smem[16384];  // 32KB: Ks [64][128] + Vs [128][64]
  ushort* Ks = smem;
  ushort* Vs = smem + 64 * 128;

  const int tid = threadIdx.x;
  const int l = tid & 63, wid = tid >> 6;
  const int lo = l & 31, hi = l >> 5;

  const int bid = blockIdx.x;                  // grid = 1024
  const int swz = (bid & 7) * 128 + (bid >> 3);
  const int h = swz >> 6;
  const int q0 = (swz & 63) * 128 + wid * 32;

  // Q fragments with rms_q * G folded in
  bf16x8 qf[8];
  {
    float ssum = 0.f;
    const float* pp = qpart + (size_t)(q0 + lo) * 32;
#pragma unroll
    for (int i = 0; i < 8; i++) {
      float4 t = *(const float4*)(pp + i * 4);
      ssum += t.x + t.y + t.z + t.w;
    }
    const float qs = rsqrtf(ssum * (1.0f / DIM) + 1e-6f);
    const ushort* qp = Qraw + (size_t)(q0 + lo) * DIM + h * HD + hi * 8;
    const float* gp = g2 + h * HD + hi * 8;
#pragma unroll
    for (int ds = 0; ds < 8; ds++) {
      union { uint4 u; ushort us[8]; } rw;
      rw.u = *(const uint4*)(qp + ds * 16);
      float4 ga_ = *(const float4*)(gp + ds * 16);
      float4 gb_ = *(const float4*)(gp + ds * 16 + 4);
      union { uint32_t w[4]; bf16x8 v; } ov;
      ov.w[0] = pk2(b2f(rw.us[0]) * qs * ga_.x, b2f(rw.us[1]) * qs * ga_.y);
      ov.w[1] = pk2(b2f(rw.us[2]) * qs * ga_.z, b2f(rw.us[3]) * qs * ga_.w);
      ov.w[2] = pk2(b2f(rw.us[4]) * qs * gb_.x, b2f(rw.us[5]) * qs * gb_.y);
      ov.w[3] = pk2(b2f(rw.us[6]) * qs * gb_.z, b2f(rw.us[7]) * qs * gb_.w);
      qf[ds] = ov.v;
    }
  }

  f32x16_t o[4] = {};          // O^T: lane q = lo, d = nt*32 + crow(r,hi)
  float m_run = -1e30f, l_run = 0.f;

  for (int kvb = 0; kvb < S_SEQ / 64; kvb++) {
    __syncthreads();
#pragma unroll
    for (int i = 0; i < 4; i++) {
      const int c = i * 256 + tid, row = c >> 4, cs = c & 15;
      gll16(Kb + (size_t)(kvb * 64 + row) * DIM + h * HD + ((cs ^ (row & 7)) * 8),
            Ks + c * 8);
    }
#pragma unroll
    for (int i = 0; i < 4; i++) {
      const int c = i * 256 + tid, row = c >> 3, cs = c & 7;
      gll16(Vt + (size_t)(h * HD + row) * S_SEQ + kvb * 64 + ((cs ^ (row & 7)) * 8),
            Vs + c * 8);
    }
    __syncthreads();

    f32x16_t sA = {}, sB = {};
#pragma unroll
    for (int ds = 0; ds < 8; ds++) {
      const int ch = ((hi + ds * 2) ^ (lo & 7)) * 8;
      bf16x8 kA = *(const bf16x8*)(Ks + lo * 128 + ch);
      bf16x8 kB = *(const bf16x8*)(Ks + (32 + lo) * 128 + ch);
      sA = __builtin_amdgcn_mfma_f32_32x32x16_bf16(kA, qf[ds], sA, 0, 0, 0);
      sB = __builtin_amdgcn_mfma_f32_32x32x16_bf16(kB, qf[ds], sB, 0, 0, 0);
    }

    float p[32];
#pragma unroll
    for (int i = 0; i < 16; i++) { p[i] = sA[i]; p[16 + i] = sB[i]; }
    float pm = p[0];
#pragma unroll
    for (int i = 1; i < 32; i++) pm = fmaxf(pm, p[i]);
    pm = fmaxf(pm, __shfl_xor(pm, 32));
    const float mn = fmaxf(m_run, pm);
    const float corr = __expf(m_run - mn);
    m_run = mn;
    float ps = 0.f;
#pragma unroll
    for (int i = 0; i < 32; i++) { p[i] = __expf(p[i] - mn); ps += p[i]; }
    ps += __shfl_xor(ps, 32);
    l_run = l_run * corr + ps;
#pragma unroll
    for (int nt = 0; nt < 4; nt++) o[nt] *= corr;

    uint32_t c[16];
#pragma unroll
    for (int j = 0; j < 16; j++) c[j] = pk2(p[2 * j], p[2 * j + 1]);
    bf16x8 pf[4];
#pragma unroll
    for (int s = 0; s < 4; s++) {
      const uint32_t ca = c[4 * s], cb = c[4 * s + 1], cc = c[4 * s + 2], cd = c[4 * s + 3];
      const uint32_t sa = __shfl_xor(ca, 32), sb = __shfl_xor(cb, 32);
      const uint32_t sc = __shfl_xor(cc, 32), sd = __shfl_xor(cd, 32);
      union { uint32_t u[4]; bf16x8 v; } f;
      f.u[0] = hi ? sc : ca; f.u[1] = hi ? sd : cb;
      f.u[2] = hi ? cc : sa; f.u[3] = hi ? cd : sb;
      pf[s] = f.v;
    }

#pragma unroll
    for (int nt = 0; nt < 4; nt++) {
      const int vrow = nt * 32 + lo;
#pragma unroll
      for (int s = 0; s < 4; s++) {
        bf16x8 vf = *(const bf16x8*)(Vs + vrow * 64 + (((s * 2 + hi) ^ (lo & 7)) * 8));
        o[nt] = __builtin_amdgcn_mfma_f32_32x32x16_bf16(vf, pf[s], o[nt], 0, 0, 0);
      }
    }
  }

  const float inv = 1.0f / l_run;
#pragma unroll
  for (int nt = 0; nt < 4; nt++) o[nt] *= inv;

  __syncthreads();
  float* tb = (float*)smem + wid * (32 * 33);
  const int q2 = l >> 1, dh = (l & 1) * 16;
#pragma unroll
  for (int nt = 0; nt < 4; nt++) {
#pragma unroll
    for (int r = 0; r < 16; r++)
      tb[lo * 33 + ((r & 3) + 8 * (r >> 2) + 4 * hi)] = o[nt][r];
    asm volatile("s_waitcnt lgkmcnt(0)" ::: "memory");
    __builtin_amdgcn_sched_barrier(0);
    ushort tmp[16];
#pragma unroll
    for (int j = 0; j < 16; j++) tmp[j] = f2b(tb[q2 * 33 + dh + j]);
    asm volatile("s_waitcnt lgkmcnt(0)" ::: "memory");
    __builtin_amdgcn_sched_barrier(0);
    const size_t oaddr = (size_t)(q0 + q2) * DIM + h * HD + nt * 32 + dh;
    *(uint4*)(Ob + oaddr) = *(uint4*)tmp;
    *(uint4*)(Ob + oaddr + 8) = *(uint4*)(tmp + 8);
  }
}

extern "C" void kernel_launch(void* const* d_in, const int* in_sizes, int n_in,
                              void* d_out, int out_size, void* d_ws, size_t ws_size,
                              hipStream_t stream) {
  const float* x   = (const float*)d_in[0];
  const float* ctx = (const float*)d_in[1];
  const float* Wq  = (const float*)d_in[2];
  const float* bq  = (const float*)d_in[3];
  const float* Wk  = (const float*)d_in[4];
  const float* bk  = (const float*)d_in[5];
  const float* Wv  = (const float*)d_in[6];
  const float* bv  = (const float*)d_in[7];
  const float* Wo  = (const float*)d_in[8];
  const float* bo  = (const float*)d_in[9];
  const float* gq  = (const float*)d_in[10];
  const float* gk  = (const float*)d_in[11];

  char* ws = (char*)d_ws;
  ushort* wqt    = (ushort*)(ws);                 // [2048][2048] bf16   8.39MB
  ushort* wkt    = (ushort*)(ws + 8388608);       // [2048][4096] bf16  16.78MB } adjacent =>
  ushort* wvt    = (ushort*)(ws + 25165824);      // [2048][4096] bf16  16.78MB } [4096][4096] KV
  ushort* wot    = (ushort*)(ws + 41943040);      // [2048][2048] bf16   8.39MB
  ushort* ctxb   = (ushort*)(ws + 50331648);      // [512][4096]  bf16   4.19MB
  float*  g2     = (float*)(ws + 54558720);       // [2048] f32   8KB
  float*  qpart  = (float*)(ws + 56623104);       // [8192][32] f32  1MB (per-block row sumsq)
  ushort* kb     = (ushort*)(ws + 83886080);      // [512][2048]  bf16   2.10MB (rms-normalized K)
  ushort* vt     = (ushort*)(ws + 85983232);      // [2048][512]  bf16   2.10MB (V^T per-head)
  ushort* xb     = (ushort*)(ws + 88080384);      // [8192][2048] bf16  33.55MB (x cast)
  ushort* kraw   = (ushort*)(ws + 88080384);      // [512][2048]  bf16   2.10MB (aliases xb; xb dead after Qproj)
  ushort* attnb  = (ushort*)(ws + 88080384);      // [8192][2048] bf16  33.55MB (aliases; kraw dead after knorm)
  ushort* qraw   = (ushort*)(ws + 121634816);     // [8192][2048] bf16  33.55MB (pre-norm Q)

  // 1. preprocessing: casts + weight transposes + G = gq*gk/sqrt(HD)
  k_prep<<<33793, 256, 0, stream>>>(x, ctx, Wq, Wk, Wv, Wo, gq, gk,
                                    xb, ctxb, wqt, wkt, wvt, wot, g2);
  // 2. Q projection: qraw = x@Wq + bq (bf16) + per-row sumsq partials -> qpart
  k_gemm256<1><<<dim3(DIM / 256, L_SEQ / 256), 512, 0, stream>>>(xb, wqt, bq, qraw, qpart, L_SEQ, DIM, DIM);
  // 3. fused K+V projection (kraw overwrites dead xb)
  k_gemmkv<<<256, 256, 0, stream>>>(ctxb, wkt, bk, bv, kraw, vt);
  // 4. K rms-normalize
  k_knorm<<<S_SEQ, 256, 0, stream>>>(kraw, kb);
  // 5. attention (rms_q from qpart, *G folded into Q-frag prep)
  k_attn<<<L_SEQ / 128 * NH, 256, 0, stream>>>(qraw, kb, vt, qpart, g2, attnb);
  // 6. out = attn @ Wo + bo (fp32)
  k_gemm256<0><<<dim3(DIM / 256, L_SEQ / 256), 512, 0, stream>>>(attnb, wot, bo, d_out, nullptr, L_SEQ, DIM, DIM);
}

// Round 13
// 312.504 us; speedup vs baseline: 2.1242x; 1.0090x over previous
//
#include <hip/hip_runtime.h>
#include <hip/hip_bf16.h>
#include <stdint.h>

#define L_SEQ 8192
#define S_SEQ 512
#define DIM   2048
#define CTX   4096
#define NH    16
#define HD    128

typedef __bf16 bf16_t;
typedef bf16_t bf16x8 __attribute__((ext_vector_type(8)));
typedef float  f32x4_t __attribute__((ext_vector_type(4)));
typedef float  f32x16_t __attribute__((ext_vector_type(16)));

__device__ __forceinline__ ushort f2b(float f) {
  bf16_t h = (bf16_t)f;
  return __builtin_bit_cast(ushort, h);
}
__device__ __forceinline__ uint32_t pk2(float a, float b) {
  return (uint32_t)f2b(a) | ((uint32_t)f2b(b) << 16);
}
__device__ __forceinline__ float b2f(ushort u) {
  union { uint32_t u; float f; } v; v.u = ((uint32_t)u) << 16;
  return v.f;
}
__device__ __forceinline__ void gll16(const ushort* g, ushort* l) {
  __builtin_amdgcn_global_load_lds((const __attribute__((address_space(1))) void*)g,
                                   (__attribute__((address_space(3))) void*)l, 16, 0, 0);
}
#define SBAR() __builtin_amdgcn_sched_barrier(0)

// ============ fused preprocessing: x/ctx casts + 4 weight transposes + G ============
__global__ __launch_bounds__(256) void k_prep(const float* __restrict__ x,
                                              const float* __restrict__ ctx,
                                              const float* __restrict__ Wq,
                                              const float* __restrict__ Wk,
                                              const float* __restrict__ Wv,
                                              const float* __restrict__ Wo,
                                              const float* __restrict__ gq,
                                              const float* __restrict__ gk,
                                              ushort* __restrict__ xb,
                                              ushort* __restrict__ ctxb,
                                              ushort* __restrict__ wqt,
                                              ushort* __restrict__ wkt,
                                              ushort* __restrict__ wvt,
                                              ushort* __restrict__ wot,
                                              float* __restrict__ g2) {
  const int b = blockIdx.x;
  const int tid = threadIdx.x;
  if (b == 33792) {  // G = gq*gk/sqrt(HD)
    const int d = tid * 8;
#pragma unroll
    for (int j = 0; j < 8; j++) g2[d + j] = gq[d + j] * gk[d + j] * 0.08838834764831843f;
    return;
  }
  if (b < 9216) {  // elementwise casts
    const float* src; ushort* dst; size_t i;
    if (b < 8192) { src = x;   dst = xb;   i = ((size_t)b * 256 + tid) * 8; }
    else          { src = ctx; dst = ctxb; i = ((size_t)(b - 8192) * 256 + tid) * 8; }
    float4 a = *(const float4*)(src + i);
    float4 c = *(const float4*)(src + i + 4);
    uint4 r;
    r.x = pk2(a.x, a.y); r.y = pk2(a.z, a.w);
    r.z = pk2(c.x, c.y); r.w = pk2(c.z, c.w);
    *(uint4*)(dst + i) = r;
    return;
  }
  // transpose + cast fp32 [K][2048] -> bf16 [2048][K]
  __shared__ float t[32][33];
  const float* src; ushort* dst; int K, ti;
  if (b < 13312)      { src = Wq; dst = wqt; K = DIM; ti = b - 9216; }
  else if (b < 21504) { src = Wk; dst = wkt; K = CTX; ti = b - 13312; }
  else if (b < 29696) { src = Wv; dst = wvt; K = CTX; ti = b - 21504; }
  else                { src = Wo; dst = wot; K = DIM; ti = b - 29696; }
  const int n0 = (ti & 63) * 32, k0 = (ti >> 6) * 32;
  const int tx = tid & 31, ty = tid >> 5;
#pragma unroll
  for (int i = 0; i < 4; i++)
    t[ty + 8 * i][tx] = src[(size_t)(k0 + ty + 8 * i) * DIM + n0 + tx];
  __syncthreads();
#pragma unroll
  for (int i = 0; i < 4; i++)
    dst[(size_t)(n0 + ty + 8 * i) * K + k0 + tx] = f2b(t[tx][ty + 8 * i]);
}

// ============ K rms-normalize (512 rows) ============
__global__ __launch_bounds__(256) void k_knorm(const ushort* __restrict__ kraw,
                                               ushort* __restrict__ kb) {
  const int row = blockIdx.x, tid = threadIdx.x;
  uint4 v = *(const uint4*)(kraw + (size_t)row * DIM + tid * 8);
  const uint32_t* vu = (const uint32_t*)&v;
  float f[8];
#pragma unroll
  for (int i = 0; i < 4; i++) {
    f[2 * i]     = b2f((ushort)(vu[i] & 0xffffu));
    f[2 * i + 1] = b2f((ushort)(vu[i] >> 16));
  }
  float s = 0.f;
#pragma unroll
  for (int i = 0; i < 8; i++) s += f[i] * f[i];
#pragma unroll
  for (int off = 32; off; off >>= 1) s += __shfl_down(s, off);
  __shared__ float wsum[4];
  __shared__ float rtot;
  if ((tid & 63) == 0) wsum[tid >> 6] = s;
  __syncthreads();
  if (tid == 0)
    rtot = rsqrtf((wsum[0] + wsum[1] + wsum[2] + wsum[3]) * (1.0f / DIM) + 1e-6f);
  __syncthreads();
  const float rms = rtot;
  ushort r[8];
#pragma unroll
  for (int i = 0; i < 8; i++) r[i] = f2b(f[i] * rms);
  *(uint4*)(kb + (size_t)row * DIM + tid * 8) = *(uint4*)r;
}

// ============== 256x256 8-wave GEMM, 8-phase / 2-K-tile schedule ==============
// Derived from the m201 template, adapted to this wave->row mapping:
//  - per phase: {ds_read subtile || stage -> barrier -> lgkmcnt(0) -> 16 MFMA -> barrier}
//  - A-LDS regions die after ph1 (waves wm read their own A-half at ph0+ph1);
//    B-regions after ph2 -> stages at ph2 (A of tile 2i+2), ph3 (B), ph6/ph7 (tile 2i+3)
//  - uniform vmcnt(8) at ph3/ph7: 16 loads outstanding -> drains exactly the
//    next-needed K-tile's 4 half-tiles; published by the following mid-barrier.
//  - prologue stages tiles 0,1 -> vmcnt(8) -> barrier. Tail iter: vmcnt(0) at ph3.
// OUT_MODE 1 additionally writes per-row partial sumsq to qpart (see epilogue).
template <int OUT_MODE>
__global__ __launch_bounds__(512, 2) void k_gemm256(const ushort* __restrict__ A,
                                                    const ushort* __restrict__ Bt,
                                                    const float* __restrict__ bias,
                                                    void* __restrict__ outp,
                                                    float* __restrict__ qpart,
                                                    int M, int N, int K) {
  __shared__ __align__(16) ushort lds[65536];  // 128 KB
  const int tid = threadIdx.x;
  const int l = tid & 63, wid = tid >> 6;
  const int wm = wid >> 2, wn = wid & 3;
  const int lr = l & 15, lq = l >> 4;

  const int nwg = gridDim.x * gridDim.y;
  const int bid = blockIdx.y * gridDim.x + blockIdx.x;
  const int swz = (bid & 7) * (nwg >> 3) + (bid >> 3);
  const int m0 = (swz / gridDim.x) * 256, n0 = (swz % gridDim.x) * 256;

  f32x4_t acc[8][4];
#pragma unroll
  for (int i = 0; i < 8; i++)
#pragma unroll
    for (int j = 0; j < 4; j++) acc[i][j] = f32x4_t{0.f, 0.f, 0.f, 0.f};

  const int srow = l >> 3;
  const int schunk = ((l & 7) ^ (srow & 7)) * 8;
  auto stage = [&](int buf, int tile, int mat, int h) {
    const ushort* gp = mat ? Bt : A;
    const int rn0 = mat ? n0 : m0;
    const size_t r0 = (size_t)(rn0 + h * 128 + wid * 8 + srow);
    const ushort* g0 = gp + r0 * K + tile * 64 + schunk;
    ushort* l0 = &lds[buf * 32768 + mat * 16384 + (h * 128 + wid * 8) * 64];
    gll16(g0, l0);
    gll16(g0 + (size_t)64 * K, l0 + 64 * 64);
  };

  auto rdA = [&](int buf, int mf, int ks) -> bf16x8 {
    const int R = wm * 128 + mf * 16 + lr;
    return *(const bf16x8*)(&lds[buf * 32768 + R * 64 + (((ks * 4 + lq) ^ (R & 7)) * 8)]);
  };
  auto rdB = [&](int buf, int nf, int ks) -> bf16x8 {
    const int R = wn * 64 + nf * 16 + lr;
    return *(const bf16x8*)(&lds[buf * 32768 + 16384 + R * 64 + (((ks * 4 + lq) ^ (R & 7)) * 8)]);
  };

  const int NT = K >> 6;   // 64-wide K-tiles (even for K=2048)
  const int NI = NT >> 1;  // 2 K-tiles per iteration

  // ---- prologue: stage tiles 0 (buf0) and 1 (buf1); publish tile 0 ----
  stage(0, 0, 0, 0); stage(0, 0, 0, 1); stage(0, 0, 1, 0); stage(0, 0, 1, 1);
  stage(1, 1, 0, 0); stage(1, 1, 0, 1); stage(1, 1, 1, 0); stage(1, 1, 1, 1);
  asm volatile("s_waitcnt vmcnt(8)" ::: "memory");  // tile 0 landed (own 8 loads drained)
  SBAR();
  __builtin_amdgcn_s_barrier();
  SBAR();

  bf16x8 a[4][2], a2[4][2], b[2][2], b2[2][2];
  for (int i = 0; i < NI; i++) {
    const bool pf = (i + 1 < NI);
#pragma unroll
    for (int half = 0; half < 2; half++) {
      const int buf = half;               // tile 2i -> buf0, 2i+1 -> buf1
      const int st = 2 * i + 2 + half;    // tile staged during this half-group
      // ---- phA: 12 reads (a, b) -> barrier -> MFMA (m0,n0) ----
#pragma unroll
      for (int mf = 0; mf < 4; mf++) { a[mf][0] = rdA(buf, mf, 0); a[mf][1] = rdA(buf, mf, 1); }
#pragma unroll
      for (int nf = 0; nf < 2; nf++) { b[nf][0] = rdB(buf, nf, 0); b[nf][1] = rdB(buf, nf, 1); }
      SBAR();
      __builtin_amdgcn_s_barrier();
      asm volatile("s_waitcnt lgkmcnt(0)" ::: "memory");
      SBAR();
      __builtin_amdgcn_s_setprio(1);
#pragma unroll
      for (int mf = 0; mf < 4; mf++)
#pragma unroll
        for (int nf = 0; nf < 2; nf++) {
          acc[mf][nf] = __builtin_amdgcn_mfma_f32_16x16x32_bf16(a[mf][0], b[nf][0], acc[mf][nf], 0, 0, 0);
          acc[mf][nf] = __builtin_amdgcn_mfma_f32_16x16x32_bf16(a[mf][1], b[nf][1], acc[mf][nf], 0, 0, 0);
        }
      __builtin_amdgcn_s_setprio(0);
      SBAR();
      __builtin_amdgcn_s_barrier();
      SBAR();
      // ---- phB: 8 reads (a2) -> barrier -> MFMA (m1,n0) ----
#pragma unroll
      for (int mf = 0; mf < 4; mf++) { a2[mf][0] = rdA(buf, mf + 4, 0); a2[mf][1] = rdA(buf, mf + 4, 1); }
      SBAR();
      __builtin_amdgcn_s_barrier();
      asm volatile("s_waitcnt lgkmcnt(0)" ::: "memory");
      SBAR();
      __builtin_amdgcn_s_setprio(1);
#pragma unroll
      for (int mf = 0; mf < 4; mf++)
#pragma unroll
        for (int nf = 0; nf < 2; nf++) {
          acc[mf + 4][nf] = __builtin_amdgcn_mfma_f32_16x16x32_bf16(a2[mf][0], b[nf][0], acc[mf + 4][nf], 0, 0, 0);
          acc[mf + 4][nf] = __builtin_amdgcn_mfma_f32_16x16x32_bf16(a2[mf][1], b[nf][1], acc[mf + 4][nf], 0, 0, 0);
        }
      __builtin_amdgcn_s_setprio(0);
      SBAR();
      __builtin_amdgcn_s_barrier();
      SBAR();
      // ---- phC: 4 reads (b2) || stage A-halves of tile st -> MFMA (m1,n1) ----
      // legal: this buf's A-regions had their last ds_read at phB (all waves synced
      // by phB's end barrier).
#pragma unroll
      for (int nf = 0; nf < 2; nf++) { b2[nf][0] = rdB(buf, nf + 2, 0); b2[nf][1] = rdB(buf, nf + 2, 1); }
      if (pf) { stage(buf, st, 0, 0); stage(buf, st, 0, 1); }
      SBAR();
      __builtin_amdgcn_s_barrier();
      asm volatile("s_waitcnt lgkmcnt(0)" ::: "memory");
      SBAR();
      __builtin_amdgcn_s_setprio(1);
#pragma unroll
      for (int mf = 0; mf < 4; mf++)
#pragma unroll
        for (int nf = 0; nf < 2; nf++) {
          acc[mf + 4][nf + 2] = __builtin_amdgcn_mfma_f32_16x16x32_bf16(a2[mf][0], b2[nf][0], acc[mf + 4][nf + 2], 0, 0, 0);
          acc[mf + 4][nf + 2] = __builtin_amdgcn_mfma_f32_16x16x32_bf16(a2[mf][1], b2[nf][1], acc[mf + 4][nf + 2], 0, 0, 0);
        }
      __builtin_amdgcn_s_setprio(0);
      SBAR();
      __builtin_amdgcn_s_barrier();
      SBAR();
      // ---- phD: stage B-halves of tile st; counted vmcnt -> MFMA (m0,n1) ----
      // legal: this buf's B-regions had their last ds_read at phC.
      // vmcnt(8): 16 loads outstanding here -> drains the 4 half-tiles of the
      // K-tile needed by the NEXT 3 phases; published at the mid-barrier below.
      if (pf) {
        stage(buf, st, 1, 0); stage(buf, st, 1, 1);
        asm volatile("s_waitcnt vmcnt(8)" ::: "memory");
      } else if (half == 0) {
        asm volatile("s_waitcnt vmcnt(0)" ::: "memory");  // tail: tile NT-1 resident
      }
      SBAR();
      __builtin_amdgcn_s_barrier();
      SBAR();
      __builtin_amdgcn_s_setprio(1);
#pragma unroll
      for (int mf = 0; mf < 4; mf++)
#pragma unroll
        for (int nf = 0; nf < 2; nf++) {
          acc[mf][nf + 2] = __builtin_amdgcn_mfma_f32_16x16x32_bf16(a[mf][0], b2[nf][0], acc[mf][nf + 2], 0, 0, 0);
          acc[mf][nf + 2] = __builtin_amdgcn_mfma_f32_16x16x32_bf16(a[mf][1], b2[nf][1], acc[mf][nf + 2], 0, 0, 0);
        }
      __builtin_amdgcn_s_setprio(0);
      SBAR();
      __builtin_amdgcn_s_barrier();
      SBAR();
    }
  }

  // ---- epilogue ----
  float bvs[4];
#pragma unroll
  for (int nf = 0; nf < 4; nf++) bvs[nf] = bias[n0 + wn * 64 + nf * 16 + lr];
#pragma unroll
  for (int nf = 0; nf < 4; nf++) {
    const int col = n0 + wn * 64 + nf * 16 + lr;
#pragma unroll
    for (int mf = 0; mf < 8; mf++) {
#pragma unroll
      for (int r = 0; r < 4; r++) {
        const int row = m0 + wm * 128 + mf * 16 + lq * 4 + r;
        const float v = acc[mf][nf][r] + bvs[nf];
        if constexpr (OUT_MODE == 0)
          ((float*)outp)[(size_t)row * N + col] = v;
        else
          ((ushort*)outp)[(size_t)row * N + col] = f2b(v);
      }
    }
  }
  if constexpr (OUT_MODE == 1) {
    const int slot = (n0 >> 8) * 4 + wn;
#pragma unroll
    for (int mf = 0; mf < 8; mf++) {
#pragma unroll
      for (int r = 0; r < 4; r++) {
        float s = 0.f;
#pragma unroll
        for (int nf = 0; nf < 4; nf++) {
          const float v = acc[mf][nf][r] + bvs[nf];
          s += v * v;
        }
        s += __shfl_xor(s, 1); s += __shfl_xor(s, 2);
        s += __shfl_xor(s, 4); s += __shfl_xor(s, 8);
        if (lr == 0)
          qpart[(size_t)(m0 + wm * 128 + mf * 16 + lq * 4 + r) * 32 + slot] = s;
      }
    }
  }
}

// ============ KV projection GEMM: M=512, N=4096, K=4096, depth-4 pipeline ============
__global__ __launch_bounds__(256) void k_gemmkv(const ushort* __restrict__ A,
                                                const ushort* __restrict__ Bt,
                                                const float* __restrict__ biasK,
                                                const float* __restrict__ biasV,
                                                ushort* __restrict__ outK,
                                                ushort* __restrict__ outVt) {
  __shared__ __align__(16) ushort As[4][128 * 32];  // 32 KB
  __shared__ __align__(16) ushort Bs[4][64 * 32];   // 16 KB
  const int tid = threadIdx.x;
  const int l = tid & 63, wid = tid >> 6;
  const int wr = wid >> 1, wc = wid & 1;
  const int lr = l & 15, lq = l >> 4;
  const int K = CTX, M = S_SEQ;

  const int bid = blockIdx.x;                 // grid = 256
  const int swz = (bid & 7) * 32 + (bid >> 3);
  const int n0 = (swz >> 2) * 64, m0 = (swz & 3) * 128;

  f32x4_t acc[4][2];
#pragma unroll
  for (int i = 0; i < 4; i++)
#pragma unroll
    for (int j = 0; j < 2; j++) acc[i][j] = f32x4_t{0.f, 0.f, 0.f, 0.f};

  const int srow = l >> 2;
  const int schunk = ((l & 3) ^ ((srow >> 1) & 3)) * 8;
  const ushort* gA = A  + (size_t)(m0 + srow) * K + schunk;
  const ushort* gB = Bt + (size_t)(n0 + wid * 16 + srow) * K + schunk;

  auto stage = [&](int buf, int kt) {
    const int ko = kt * 32;
    gll16(gA + (size_t)(wid * 16) * K + ko,      &As[buf][(wid * 16) * 32]);
    gll16(gA + (size_t)(64 + wid * 16) * K + ko, &As[buf][(64 + wid * 16) * 32]);
    gll16(gB + ko,                               &Bs[buf][(wid * 16) * 32]);
  };
  auto rdA = [&](int buf, int mi) -> bf16x8 {
    const int R = wr * 64 + mi * 16 + lr;
    return *(const bf16x8*)(&As[buf][R * 32 + ((lq ^ ((R >> 1) & 3)) * 8)]);
  };
  auto rdB = [&](int buf, int ni) -> bf16x8 {
    const int R = wc * 32 + ni * 16 + lr;
    return *(const bf16x8*)(&Bs[buf][R * 32 + ((lq ^ ((R >> 1) & 3)) * 8)]);
  };

  const int NT = K >> 5;  // 128
  stage(0, 0); stage(1, 1); stage(2, 2);
  for (int t = 0; t < NT; t++) {
    const int cur = t & 3;
    if (t + 3 < NT) { stage((t + 3) & 3, t + 3); asm volatile("s_waitcnt vmcnt(9)" ::: "memory"); }
    else if (t + 2 < NT) { asm volatile("s_waitcnt vmcnt(6)" ::: "memory"); }
    else if (t + 1 < NT) { asm volatile("s_waitcnt vmcnt(3)" ::: "memory"); }
    else                 { asm volatile("s_waitcnt vmcnt(0)" ::: "memory"); }
    SBAR();
    __builtin_amdgcn_s_barrier();
    SBAR();

    bf16x8 af[4], bfr[2];
#pragma unroll
    for (int mi = 0; mi < 4; mi++) af[mi] = rdA(cur, mi);
#pragma unroll
    for (int ni = 0; ni < 2; ni++) bfr[ni] = rdB(cur, ni);
    __builtin_amdgcn_s_setprio(1);
#pragma unroll
    for (int mi = 0; mi < 4; mi++)
#pragma unroll
      for (int ni = 0; ni < 2; ni++)
        acc[mi][ni] = __builtin_amdgcn_mfma_f32_16x16x32_bf16(af[mi], bfr[ni], acc[mi][ni], 0, 0, 0);
    __builtin_amdgcn_s_setprio(0);
    SBAR();
    __builtin_amdgcn_s_barrier();
    SBAR();
  }

  if (n0 < DIM) {
#pragma unroll
    for (int mi = 0; mi < 4; mi++) {
#pragma unroll
      for (int ni = 0; ni < 2; ni++) {
        const int col = n0 + wc * 32 + ni * 16 + lr;
        const float bv = biasK[col];
#pragma unroll
        for (int r = 0; r < 4; r++) {
          const int row = m0 + wr * 64 + mi * 16 + lq * 4 + r;
          outK[(size_t)row * DIM + col] = f2b(acc[mi][ni][r] + bv);
        }
      }
    }
  } else {
    // V block: transpose through LDS for coalesced V^T stores
    ushort* ldst = &As[0][0];
    __syncthreads();
#pragma unroll
    for (int mi = 0; mi < 4; mi++) {
#pragma unroll
      for (int ni = 0; ni < 2; ni++) {
        const int ccol = wc * 32 + ni * 16 + lr;
        const float bv = biasV[n0 - DIM + ccol];
#pragma unroll
        for (int r = 0; r < 4; r++) {
          const int crow = wr * 64 + mi * 16 + lq * 4 + r;
          ldst[ccol * 128 + crow] = f2b(acc[mi][ni][r] + bv);
        }
      }
    }
    __syncthreads();
    const int c = tid >> 2, j0 = (tid & 3) * 32;
    ushort* dst = outVt + (size_t)(n0 - DIM + c) * M + m0 + j0;
#pragma unroll
    for (int k2 = 0; k2 < 4; k2++)
      *(uint4*)(dst + k2 * 8) = *(const uint4*)(ldst + c * 128 + j0 + k2 * 8);
  }
}

// ============ Flash attention, swapped-operand 32x32x16 ============
__global__ __launch_bounds__(256) void k_attn(const ushort* __restrict__ Qraw,
                                              const ushort* __restrict__ Kb,
                                              const ushort* __restrict__ Vt,
                                              const float* __restrict__ qpart,
                                              const float* __restrict__ g2,
                                              ushort* __restrict__ Ob) {
  __shared__ __align__(16) ushort smem[16384];  // 32KB: Ks [64][128] + Vs [128][64]
  ushort* Ks = smem;
  ushort* Vs = smem + 64 * 128;

  const int tid = threadIdx.x;
  const int l = tid & 63, wid = tid >> 6;
  const int lo = l & 31, hi = l >> 5;

  const int bid = blockIdx.x;                  // grid = 1024
  const int swz = (bid & 7) * 128 + (bid >> 3);
  const int h = swz >> 6;
  const int q0 = (swz & 63) * 128 + wid * 32;

  bf16x8 qf[8];
  {
    float ssum = 0.f;
    const float* pp = qpart + (size_t)(q0 + lo) * 32;
#pragma unroll
    for (int i = 0; i < 8; i++) {
      float4 t = *(const float4*)(pp + i * 4);
      ssum += t.x + t.y + t.z + t.w;
    }
    const float qs = rsqrtf(ssum * (1.0f / DIM) + 1e-6f);
    const ushort* qp = Qraw + (size_t)(q0 + lo) * DIM + h * HD + hi * 8;
    const float* gp = g2 + h * HD + hi * 8;
#pragma unroll
    for (int ds = 0; ds < 8; ds++) {
      union { uint4 u; ushort us[8]; } rw;
      rw.u = *(const uint4*)(qp + ds * 16);
      float4 ga_ = *(const float4*)(gp + ds * 16);
      float4 gb_ = *(const float4*)(gp + ds * 16 + 4);
      union { uint32_t w[4]; bf16x8 v; } ov;
      ov.w[0] = pk2(b2f(rw.us[0]) * qs * ga_.x, b2f(rw.us[1]) * qs * ga_.y);
      ov.w[1] = pk2(b2f(rw.us[2]) * qs * ga_.z, b2f(rw.us[3]) * qs * ga_.w);
      ov.w[2] = pk2(b2f(rw.us[4]) * qs * gb_.x, b2f(rw.us[5]) * qs * gb_.y);
      ov.w[3] = pk2(b2f(rw.us[6]) * qs * gb_.z, b2f(rw.us[7]) * qs * gb_.w);
      qf[ds] = ov.v;
    }
  }

  f32x16_t o[4] = {};          // O^T: lane q = lo, d = nt*32 + crow(r,hi)
  float m_run = -1e30f, l_run = 0.f;

  for (int kvb = 0; kvb < S_SEQ / 64; kvb++) {
    __syncthreads();
#pragma unroll
    for (int i = 0; i < 4; i++) {
      const int c = i * 256 + tid, row = c >> 4, cs = c & 15;
      gll16(Kb + (size_t)(kvb * 64 + row) * DIM + h * HD + ((cs ^ (row & 7)) * 8),
            Ks + c * 8);
    }
#pragma unroll
    for (int i = 0; i < 4; i++) {
      const int c = i * 256 + tid, row = c >> 3, cs = c & 7;
      gll16(Vt + (size_t)(h * HD + row) * S_SEQ + kvb * 64 + ((cs ^ (row & 7)) * 8),
            Vs + c * 8);
    }
    __syncthreads();

    f32x16_t sA = {}, sB = {};
#pragma unroll
    for (int ds = 0; ds < 8; ds++) {
      const int ch = ((hi + ds * 2) ^ (lo & 7)) * 8;
      bf16x8 kA = *(const bf16x8*)(Ks + lo * 128 + ch);
      bf16x8 kB = *(const bf16x8*)(Ks + (32 + lo) * 128 + ch);
      sA = __builtin_amdgcn_mfma_f32_32x32x16_bf16(kA, qf[ds], sA, 0, 0, 0);
      sB = __builtin_amdgcn_mfma_f32_32x32x16_bf16(kB, qf[ds], sB, 0, 0, 0);
    }

    float p[32];
#pragma unroll
    for (int i = 0; i < 16; i++) { p[i] = sA[i]; p[16 + i] = sB[i]; }
    float pm = p[0];
#pragma unroll
    for (int i = 1; i < 32; i++) pm = fmaxf(pm, p[i]);
    pm = fmaxf(pm, __shfl_xor(pm, 32));
    const float mn = fmaxf(m_run, pm);
    const float corr = __expf(m_run - mn);
    m_run = mn;
    float ps = 0.f;
#pragma unroll
    for (int i = 0; i < 32; i++) { p[i] = __expf(p[i] - mn); ps += p[i]; }
    ps += __shfl_xor(ps, 32);
    l_run = l_run * corr + ps;
#pragma unroll
    for (int nt = 0; nt < 4; nt++) o[nt] *= corr;

    uint32_t c[16];
#pragma unroll
    for (int j = 0; j < 16; j++) c[j] = pk2(p[2 * j], p[2 * j + 1]);
    bf16x8 pf[4];
#pragma unroll
    for (int s = 0; s < 4; s++) {
      const uint32_t ca = c[4 * s], cb = c[4 * s + 1], cc = c[4 * s + 2], cd = c[4 * s + 3];
      const uint32_t sa = __shfl_xor(ca, 32), sb = __shfl_xor(cb, 32);
      const uint32_t sc = __shfl_xor(cc, 32), sd = __shfl_xor(cd, 32);
      union { uint32_t u[4]; bf16x8 v; } f;
      f.u[0] = hi ? sc : ca; f.u[1] = hi ? sd : cb;
      f.u[2] = hi ? cc : sa; f.u[3] = hi ? cd : sb;
      pf[s] = f.v;
    }

#pragma unroll
    for (int nt = 0; nt < 4; nt++) {
      const int vrow = nt * 32 + lo;
#pragma unroll
      for (int s = 0; s < 4; s++) {
        bf16x8 vf = *(const bf16x8*)(Vs + vrow * 64 + (((s * 2 + hi) ^ (lo & 7)) * 8));
        o[nt] = __builtin_amdgcn_mfma_f32_32x32x16_bf16(vf, pf[s], o[nt], 0, 0, 0);
      }
    }
  }

  const float inv = 1.0f / l_run;
#pragma unroll
  for (int nt = 0; nt < 4; nt++) o[nt] *= inv;

  __syncthreads();
  float* tb = (float*)smem + wid * (32 * 33);
  const int q2 = l >> 1, dh = (l & 1) * 16;
#pragma unroll
  for (int nt = 0; nt < 4; nt++) {
#pragma unroll
    for (int r = 0; r < 16; r++)
      tb[lo * 33 + ((r & 3) + 8 * (r >> 2) + 4 * hi)] = o[nt][r];
    asm volatile("s_waitcnt lgkmcnt(0)" ::: "memory");
    SBAR();
    ushort tmp[16];
#pragma unroll
    for (int j = 0; j < 16; j++) tmp[j] = f2b(tb[q2 * 33 + dh + j]);
    asm volatile("s_waitcnt lgkmcnt(0)" ::: "memory");
    SBAR();
    const size_t oaddr = (size_t)(q0 + q2) * DIM + h * HD + nt * 32 + dh;
    *(uint4*)(Ob + oaddr) = *(uint4*)tmp;
    *(uint4*)(Ob + oaddr + 8) = *(uint4*)(tmp + 8);
  }
}

extern "C" void kernel_launch(void* const* d_in, const int* in_sizes, int n_in,
                              void* d_out, int out_size, void* d_ws, size_t ws_size,
                              hipStream_t stream) {
  const float* x   = (const float*)d_in[0];
  const float* ctx = (const float*)d_in[1];
  const float* Wq  = (const float*)d_in[2];
  const float* bq  = (const float*)d_in[3];
  const float* Wk  = (const float*)d_in[4];
  const float* bk  = (const float*)d_in[5];
  const float* Wv  = (const float*)d_in[6];
  const float* bv  = (const float*)d_in[7];
  const float* Wo  = (const float*)d_in[8];
  const float* bo  = (const float*)d_in[9];
  const float* gq  = (const float*)d_in[10];
  const float* gk  = (const float*)d_in[11];

  char* ws = (char*)d_ws;
  ushort* wqt    = (ushort*)(ws);                 // [2048][2048] bf16   8.39MB
  ushort* wkt    = (ushort*)(ws + 8388608);       // [2048][4096] bf16  16.78MB } adjacent =>
  ushort* wvt    = (ushort*)(ws + 25165824);      // [2048][4096] bf16  16.78MB } [4096][4096] KV
  ushort* wot    = (ushort*)(ws + 41943040);      // [2048][2048] bf16   8.39MB
  ushort* ctxb   = (ushort*)(ws + 50331648);      // [512][4096]  bf16   4.19MB
  float*  g2     = (float*)(ws + 54558720);       // [2048] f32   8KB
  float*  qpart  = (float*)(ws + 56623104);       // [8192][32] f32  1MB
  ushort* kb     = (ushort*)(ws + 83886080);      // [512][2048]  bf16   2.10MB
  ushort* vt     = (ushort*)(ws + 85983232);      // [2048][512]  bf16   2.10MB
  ushort* xb     = (ushort*)(ws + 88080384);      // [8192][2048] bf16  33.55MB
  ushort* kraw   = (ushort*)(ws + 88080384);      // aliases xb (dead after Qproj)
  ushort* attnb  = (ushort*)(ws + 88080384);      // aliases (kraw dead after knorm)
  ushort* qraw   = (ushort*)(ws + 121634816);     // [8192][2048] bf16  33.55MB

  // 1. preprocessing: casts + weight transposes + G
  k_prep<<<33793, 256, 0, stream>>>(x, ctx, Wq, Wk, Wv, Wo, gq, gk,
                                    xb, ctxb, wqt, wkt, wvt, wot, g2);
  // 2. Q projection: qraw = x@Wq + bq (bf16) + per-row sumsq partials -> qpart
  k_gemm256<1><<<dim3(DIM / 256, L_SEQ / 256), 512, 0, stream>>>(xb, wqt, bq, qraw, qpart, L_SEQ, DIM, DIM);
  // 3. fused K+V projection
  k_gemmkv<<<256, 256, 0, stream>>>(ctxb, wkt, bk, bv, kraw, vt);
  // 4. K rms-normalize
  k_knorm<<<S_SEQ, 256, 0, stream>>>(kraw, kb);
  // 5. attention
  k_attn<<<L_SEQ / 128 * NH, 256, 0, stream>>>(qraw, kb, vt, qpart, g2, attnb);
  // 6. out = attn @ Wo + bo (fp32)
  k_gemm256<0><<<dim3(DIM / 256, L_SEQ / 256), 512, 0, stream>>>(attnb, wot, bo, d_out, nullptr, L_SEQ, DIM, DIM);
}